// Round 15
// baseline (306.042 us; speedup 1.0000x reference)
//
#include <hip/hip_runtime.h>
#include <math.h>

#define NN 50000
#define NE 800000
#define NRT 782          // row tiles of 64
#define NT  (NRT * 2)    // x2 col-halves = 1564 blocks (mega1 triple-GEMM)
#define NB  128          // coarse dst-buckets
#define NPB2 391         // nodes per bucket
#define EPB 2048         // edges per bucketize block
#define NBB 391          // bucketize blocks

typedef __attribute__((ext_vector_type(8))) short short8;
typedef __attribute__((ext_vector_type(4))) float floatx4;

#define AS1 __attribute__((address_space(1)))
#define AS3 __attribute__((address_space(3)))

__device__ __forceinline__ unsigned short f2bf(float f) {
    unsigned u = __float_as_uint(f);
    unsigned r = (u + 0x7fff + ((u >> 16) & 1)) >> 16;
    return (unsigned short)r;
}
__device__ __forceinline__ float bf2f(unsigned short h) {
    return __uint_as_float(((unsigned)h) << 16);
}

// ---------------- prep: cvt (h->bf16) | bucket-count | packW ----------------

__global__ __launch_bounds__(256)
void k_prep(const float* __restrict__ h, unsigned short* __restrict__ hB,
            const int* __restrict__ dst, int* __restrict__ bcnt,
            const float* w0, const float* w1, const float* w2, const float* w3,
            const float* w4, const float* w5, const float* w6, const float* w7,
            short* __restrict__ wpk) {
    int bid = blockIdx.x;
    const int t = threadIdx.x;
    if (bid < 3125) {              // cvt
        int i = (bid * 256 + t) * 8;
        float4 a = *(const float4*)&h[i];
        float4 b = *(const float4*)&h[i + 4];
        short8 v;
        v[0] = (short)f2bf(a.x); v[1] = (short)f2bf(a.y);
        v[2] = (short)f2bf(a.z); v[3] = (short)f2bf(a.w);
        v[4] = (short)f2bf(b.x); v[5] = (short)f2bf(b.y);
        v[6] = (short)f2bf(b.z); v[7] = (short)f2bf(b.w);
        *(short8*)&hB[i] = v;
    } else if (bid < 3125 + NBB) { // bucket-count
        __shared__ int cnt[NB];
        if (t < NB) cnt[t] = 0;
        __syncthreads();
        int base = (bid - 3125) * EPB;
#pragma unroll
        for (int i = 0; i < 8; ++i) {
            int idx = base + i * 256 + t;
            if (idx < NE) atomicAdd(&cnt[dst[idx] / NPB2], 1);
        }
        __syncthreads();
        if (t < NB && cnt[t]) atomicAdd(&bcnt[t], cnt[t]);
    } else {                       // packW, 8 blocks
        int wb = bid - 3125 - NBB;
        const float* W;
        switch (wb) {
            case 0: W = w0; break; case 1: W = w1; break;
            case 2: W = w2; break; case 3: W = w3; break;
            case 4: W = w4; break; case 5: W = w5; break;
            case 6: W = w6; break; default: W = w7; break;
        }
        short* dstp = wpk + (size_t)wb * 16384;
#pragma unroll
        for (int i = 0; i < 8; ++i) {
            int q = t + i * 256;
            int cb = q >> 8, ks = (q >> 6) & 3, lane = q & 63;
            int n = lane & 15, g = lane >> 4;
            int col = cb * 16 + n, krow = ks * 32 + g * 8;
            short8 v;
#pragma unroll
            for (int j = 0; j < 8; ++j)
                v[j] = (short)f2bf(W[(krow + j) * 128 + col]);
            *(short8*)&dstp[q * 8] = v;
        }
    }
}

// ---------------- bscan: 128-wide prefix -> gcur + bstart ----------------

__global__ void k_bscan(const int* __restrict__ bcnt, int* __restrict__ gcur,
                        int* __restrict__ bstart) {
    __shared__ int s[NB];
    int t = threadIdx.x;
    int c = bcnt[t];
    s[t] = c;
    __syncthreads();
    for (int off = 1; off < NB; off <<= 1) {
        int v = (t >= off) ? s[t - off] : 0;
        __syncthreads();
        s[t] += v;
        __syncthreads();
    }
    int excl = s[t] - c;
    gcur[t] = excl;
    bstart[t] = excl;
    if (t == NB - 1) bstart[NB] = s[NB - 1];
}

// ---------------- bucketize ----------------

__global__ __launch_bounds__(256)
void k_bucket(const int* __restrict__ src, const int* __restrict__ dst,
              int* __restrict__ gcur, int* __restrict__ bsrc, int* __restrict__ bdst) {
    __shared__ int psrc[EPB];
    __shared__ int pdst[EPB];
    __shared__ int cnt[NB];
    __shared__ int ebase[NB];
    __shared__ int gbase[NB];
    const int t = threadIdx.x;
    const int e0 = blockIdx.x * EPB;
    const int M = (e0 + EPB <= NE) ? EPB : (NE - e0);

    if (t < NB) cnt[t] = 0;
    __syncthreads();

    int es[8], ed[8], rank[8];
#pragma unroll
    for (int i = 0; i < 8; ++i) {
        int idx = i * 256 + t;
        if (idx < M) {
            es[i] = src[e0 + idx];
            ed[i] = dst[e0 + idx];
            rank[i] = atomicAdd(&cnt[ed[i] / NPB2], 1);
        }
    }
    __syncthreads();
    if (t < NB) ebase[t] = cnt[t];
    __syncthreads();
    for (int off = 1; off < NB; off <<= 1) {
        int v = 0;
        if (t < NB && t >= off) v = ebase[t - off];
        __syncthreads();
        if (t < NB) ebase[t] += v;
        __syncthreads();
    }
    if (t < NB) ebase[t] -= cnt[t];
    __syncthreads();
#pragma unroll
    for (int i = 0; i < 8; ++i) {
        int idx = i * 256 + t;
        if (idx < M) {
            int b = ed[i] / NPB2;
            int pos = ebase[b] + rank[i];
            psrc[pos] = es[i];
            pdst[pos] = ed[i];
        }
    }
    if (t < NB && cnt[t] > 0) gbase[t] = atomicAdd(&gcur[t], cnt[t]);
    __syncthreads();
#pragma unroll
    for (int i = 0; i < 8; ++i) {
        int idx = i * 256 + t;
        if (idx < M) {
            int d = pdst[idx];
            int b = d / NPB2;
            int gpos = gbase[b] + (idx - ebase[b]);
            bsrc[gpos] = psrc[idx];
            bdst[gpos] = d;
        }
    }
}

// ---------------- shared GEMM helpers ----------------

__device__ __forceinline__ void drain_barrier() {
    asm volatile("s_waitcnt vmcnt(0)" ::: "memory");
    __builtin_amdgcn_sched_barrier(0);
    __syncthreads();
}

// stage full 128-col packed W (32 KB)
__device__ __forceinline__ void stage_w128(const short* Wc, short* sW, int wv, int lane) {
#pragma unroll
    for (int i = 0; i < 8; ++i) {
        int cbase = (i * 4 + wv) * 64;
        __builtin_amdgcn_global_load_lds(
            (const AS1 unsigned int*)(Wc + (size_t)(cbase + lane) * 8),
            (AS3 unsigned int*)(sW + cbase * 8), 16, 0, 0);
    }
}

// stage 64-row A tile (16 KB), XOR-swizzled source
__device__ __forceinline__ void stage_a64(const unsigned short* Ac, short* sX, int row0,
                                          int wv, int lane) {
#pragma unroll
    for (int i = 0; i < 4; ++i) {
        int cbase = (i * 4 + wv) * 64;
        int id = cbase + lane;
        int r = id >> 4, cs = id & 15;
        int rg = row0 + r; if (rg >= NN) rg = NN - 1;
        int csrc = cs ^ (r & 7);
        __builtin_amdgcn_global_load_lds(
            (const AS1 unsigned int*)(Ac + (size_t)rg * 128 + csrc * 8),
            (AS3 unsigned int*)(sX + cbase * 8), 16, 0, 0);
    }
}

// 64 rows x 128 cols MFMA pass; wave wv owns rows wv*16..+15
__device__ __forceinline__ void mm128(const short* sX, const short* sW, int wv, int lane,
                                      floatx4 acc[8]) {
    const int m = lane & 15, g = lane >> 4;
    const int r0 = wv * 16;
#pragma unroll
    for (int ks = 0; ks < 4; ++ks) {
        int slot = (ks * 4 + g) ^ (m & 7);
        short8 af = *(const short8*)&sX[((r0 + m) * 16 + slot) * 8];
#pragma unroll
        for (int cb = 0; cb < 8; ++cb) {
            short8 bf = *(const short8*)&sW[((cb * 4 + ks) * 64 + lane) * 8];
            acc[cb] = __builtin_amdgcn_mfma_f32_16x16x32_bf16(af, bf, acc[cb], 0, 0, 0);
        }
    }
}

// bias+ELU on acc -> bf16 into sX (A-frag layout, wave-local rows); zero acc
__device__ __forceinline__ void act_to_lds64(short* sX, const float* bias, int wv, int lane,
                                             floatx4 acc[8]) {
    const int m = lane & 15, g = lane >> 4;
#pragma unroll
    for (int cb = 0; cb < 8; ++cb) {
        int C = cb * 16 + m;
        float bb = bias[C];
#pragma unroll
        for (int rr = 0; rr < 4; ++rr) {
            int Rl = wv * 16 + g * 4 + rr;
            float v = acc[cb][rr] + bb;
            v = (v > 0.f) ? v : expm1f(v);
            int slot = (C >> 3) ^ (Rl & 7);
            sX[(Rl * 16 + slot) * 8 + (C & 7)] = (short)f2bf(v);
        }
    }
#pragma unroll
    for (int cb = 0; cb < 8; ++cb) acc[cb] = (floatx4){0.f, 0.f, 0.f, 0.f};
}

// per-wave gather of one node's 128 cols (2-edge groups); result on lanes<32, 4 cols each
__device__ __forceinline__ void gather4(const unsigned short* __restrict__ F,
                                        const int* __restrict__ col_idx,
                                        int beg, int end, int grp, size_t lo,
                                        float& a0, float& a1, float& a2, float& a3) {
    a0 = a1 = a2 = a3 = 0.f;
    int j = beg;
#pragma unroll 1
    for (; j + 8 <= end; j += 8) {
        int s[4];
#pragma unroll
        for (int u = 0; u < 4; ++u) s[u] = col_idx[j + 2 * u + grp];
        uint2 v[4];
#pragma unroll
        for (int u = 0; u < 4; ++u)
            v[u] = *(const uint2*)&F[(size_t)s[u] * 128 + lo];
#pragma unroll
        for (int u = 0; u < 4; ++u) {
            a0 += bf2f((unsigned short)(v[u].x & 0xffff));
            a1 += bf2f((unsigned short)(v[u].x >> 16));
            a2 += bf2f((unsigned short)(v[u].y & 0xffff));
            a3 += bf2f((unsigned short)(v[u].y >> 16));
        }
    }
#pragma unroll 1
    for (; j < end; j += 2) {
        int e = j + grp;
        if (e < end) {
            int s = col_idx[e];
            uint2 v = *(const uint2*)&F[(size_t)s * 128 + lo];
            a0 += bf2f((unsigned short)(v.x & 0xffff));
            a1 += bf2f((unsigned short)(v.x >> 16));
            a2 += bf2f((unsigned short)(v.y & 0xffff));
            a3 += bf2f((unsigned short)(v.y >> 16));
        }
    }
    a0 += __shfl_xor(a0, 32);
    a1 += __shfl_xor(a1, 32);
    a2 += __shfl_xor(a2, 32);
    a3 += __shfl_xor(a3, 32);
}

// ---------------- triple-GEMM (T1, C1, S1) for mega1 ----------------

__device__ __forceinline__ void gemm3_body(
        int bid, const unsigned short* __restrict__ A,
        const short* __restrict__ Wn, const short* __restrict__ Ws,
        const short* __restrict__ Wk, const float* __restrict__ bsk1,
        unsigned short* __restrict__ T1, unsigned short* __restrict__ C1,
        unsigned short* __restrict__ S1, short* sW, short* sA) {
    const int t = threadIdx.x;
    const int wv = t >> 6, lane = t & 63;
    const int rb = bid >> 1, ct = bid & 1;
    const int row0 = rb * 64, col0 = ct * 64;
    const int m = lane & 15, g = lane >> 4;

    // stage A once
#pragma unroll
    for (int i = 0; i < 4; ++i) {
        int cbase = (i * 4 + wv) * 64;
        int id = cbase + lane;
        int r = id >> 4, cs = id & 15;
        int rg = row0 + r; if (rg >= NN) rg = NN - 1;
        int csrc = cs ^ (r & 7);
        __builtin_amdgcn_global_load_lds(
            (const AS1 unsigned int*)(A + (size_t)rg * 128 + csrc * 8),
            (AS3 unsigned int*)(sA + cbase * 8), 16, 0, 0);
    }

#pragma unroll
    for (int ph = 0; ph < 3; ++ph) {
        if (ph) __syncthreads();
        const short* Wc = (ph == 0 ? Wn : ph == 1 ? Ws : Wk) + ct * 8192;
#pragma unroll
        for (int i = 0; i < 4; ++i) {
            int cbase = (i * 4 + wv) * 64;
            __builtin_amdgcn_global_load_lds(
                (const AS1 unsigned int*)(Wc + (size_t)(cbase + lane) * 8),
                (AS3 unsigned int*)(sW + cbase * 8), 16, 0, 0);
        }
        drain_barrier();

        floatx4 acc[4];
#pragma unroll
        for (int cb = 0; cb < 4; ++cb) acc[cb] = (floatx4){0.f, 0.f, 0.f, 0.f};
        const int r0 = wv * 16;
#pragma unroll
        for (int ks = 0; ks < 4; ++ks) {
            int cxor = (ks * 4 + g) ^ (m & 7);
            short8 af = *(const short8*)&sA[((r0 + m) * 16 + cxor) * 8];
#pragma unroll
            for (int cb = 0; cb < 4; ++cb) {
                short8 bf = *(const short8*)&sW[((cb * 4 + ks) * 64 + lane) * 8];
                acc[cb] = __builtin_amdgcn_mfma_f32_16x16x32_bf16(af, bf, acc[cb], 0, 0, 0);
            }
        }

        const int rowbase = row0 + wv * 16 + g * 4;
#pragma unroll
        for (int cb = 0; cb < 4; ++cb) {
            int C = col0 + cb * 16 + m;
            float bb = (ph == 2) ? bsk1[C] : 0.f;
#pragma unroll
            for (int rr = 0; rr < 4; ++rr) {
                int R = rowbase + rr;
                if (R < NN) {
                    size_t idx = (size_t)R * 128 + C;
                    float v = acc[cb][rr] + bb;
                    if (ph == 0)      T1[idx] = f2bf(v);
                    else if (ph == 1) C1[idx] = f2bf(v);
                    else {
                        v = (v > 0.f) ? v : expm1f(v);
                        S1[idx] = f2bf(v);
                    }
                }
            }
        }
    }
}

// ---------------- mega1: per-bucket scatter+CSR || triple-GEMM ----------------

__global__ __launch_bounds__(256)
void k_mega1(const int* __restrict__ bsrc, const int* __restrict__ bdst,
             const int* __restrict__ bstart, int* __restrict__ row_start,
             int* __restrict__ col_idx,
             const unsigned short* __restrict__ hB, const short* __restrict__ wpk,
             const float* __restrict__ bsk1,
             unsigned short* __restrict__ T1out, unsigned short* __restrict__ C1out,
             unsigned short* __restrict__ S1out) {
    __shared__ short sMem[16384];
    int bid = blockIdx.x;
    if (bid < NB) {
        int* lcur = (int*)sMem;          // [NPB2]
        int* sc   = lcur + NPB2;         // [512]
        int* rs   = sc + 512;            // [NPB2]
        const int t = threadIdx.x;
        const int n0 = bid * NPB2;
        const int n1 = (n0 + NPB2 < NN) ? n0 + NPB2 : NN;
        const int nn = n1 - n0;
        const int w0 = bstart[bid], w1 = bstart[bid + 1];
        for (int i = t; i < nn; i += 256) lcur[i] = 0;
        __syncthreads();
        for (int e = w0 + t; e < w1; e += 256)
            atomicAdd(&lcur[bdst[e] - n0], 1);
        __syncthreads();
        int v0 = (t < nn) ? lcur[t] : 0;
        int v1 = (t + 256 < nn) ? lcur[t + 256] : 0;
        sc[t] = v0; sc[t + 256] = v1;
        __syncthreads();
        for (int off = 1; off < 512; off <<= 1) {
            int a0 = (t >= off) ? sc[t - off] : 0;
            int a1 = (t + 256 >= off) ? sc[t + 256 - off] : 0;
            __syncthreads();
            sc[t] += a0; sc[t + 256] += a1;
            __syncthreads();
        }
        for (int i = t; i < nn; i += 256) {
            int r = w0 + sc[i] - lcur[i];
            rs[i] = r;
            row_start[n0 + i] = r;
            lcur[i] = 0;
        }
        if (bid == 0 && t == 0) row_start[NN] = NE;
        __syncthreads();
        for (int e = w0 + t; e < w1; e += 256) {
            int d = bdst[e] - n0;
            int slot = atomicAdd(&lcur[d], 1);
            col_idx[rs[d] + slot] = bsrc[e];
        }
    } else {
        gemm3_body(bid - NB, hB, wpk + 3 * 16384 /*neigh1*/, wpk + 2 * 16384 /*self1*/,
                   wpk /*skip1*/, bsk1, T1out, C1out, S1out, sMem, sMem + 8192);
    }
}

// ---------------- fuse1: X1=ELU(C1+mean(T1)+bc) [LDS] -> si1 -> si2 -> X3 ----------------

__global__ __launch_bounds__(256)
void k_fuse1(const unsigned short* __restrict__ T1, const int* __restrict__ row_start,
             const int* __restrict__ col_idx, const unsigned short* __restrict__ C1,
             const float* __restrict__ bc, const short* __restrict__ WpSi1,
             const short* __restrict__ WpSi2, const float* __restrict__ bs1,
             const float* __restrict__ bs2, unsigned short* __restrict__ X3out) {
    __shared__ short sW[16384];   // 32 KB
    __shared__ short sX[8192];    // 16 KB
    const int t = threadIdx.x, wv = t >> 6, lane = t & 63;
    const int row0 = blockIdx.x * 64;
    const int grp = lane >> 5, gl = lane & 31;

    stage_w128(WpSi1, sW, wv, lane);   // hide W staging under the gather

    // phase A: gather X1 rows (wave-local) into sX
#pragma unroll 1
    for (int k = 0; k < 16; ++k) {
        int node = row0 + wv * 16 + k;
        if (node < NN) {
            int beg = row_start[node], end = row_start[node + 1];
            size_t lo = (size_t)(gl * 4);
            float a0, a1, a2, a3;
            gather4(T1, col_idx, beg, end, grp, lo, a0, a1, a2, a3);
            if (lane < 32) {
                float inv = 1.0f / fmaxf((float)(end - beg), 1.0f);
                uint2 c = *(const uint2*)&C1[(size_t)node * 128 + lo];
                float4 bv = *(const float4*)&bc[gl * 4];
                float x0 = a0 * inv + bf2f((unsigned short)(c.x & 0xffff)) + bv.x;
                float x1 = a1 * inv + bf2f((unsigned short)(c.x >> 16)) + bv.y;
                float x2 = a2 * inv + bf2f((unsigned short)(c.y & 0xffff)) + bv.z;
                float x3 = a3 * inv + bf2f((unsigned short)(c.y >> 16)) + bv.w;
                x0 = (x0 > 0.f) ? x0 : expm1f(x0);
                x1 = (x1 > 0.f) ? x1 : expm1f(x1);
                x2 = (x2 > 0.f) ? x2 : expm1f(x2);
                x3 = (x3 > 0.f) ? x3 : expm1f(x3);
                int Rl = wv * 16 + k;
                int slot = (gl >> 1) ^ (Rl & 7);
                unsigned* p = (unsigned*)&sX[(Rl * 16 + slot) * 8 + (gl & 1) * 4];
                p[0] = (unsigned)f2bf(x0) | ((unsigned)f2bf(x1) << 16);
                p[1] = (unsigned)f2bf(x2) | ((unsigned)f2bf(x3) << 16);
            }
        }
    }

    floatx4 acc[8];
#pragma unroll
    for (int cb = 0; cb < 8; ++cb) acc[cb] = (floatx4){0.f, 0.f, 0.f, 0.f};
    drain_barrier();
    mm128(sX, sW, wv, lane, acc);      // X1 @ Wsi1

    __syncthreads();
    act_to_lds64(sX, bs1, wv, lane, acc);   // Y1 -> sX, acc zeroed
    stage_w128(WpSi2, sW, wv, lane);
    drain_barrier();
    mm128(sX, sW, wv, lane, acc);      // Y1 @ Wsi2

    // epilogue: +bs2, ELU -> X3 global
    const int m = lane & 15, g = lane >> 4;
    const int rowbase = row0 + wv * 16 + g * 4;
#pragma unroll
    for (int cb = 0; cb < 8; ++cb) {
        int C = cb * 16 + m;
        float bb = bs2[C];
#pragma unroll
        for (int rr = 0; rr < 4; ++rr) {
            int R = rowbase + rr;
            if (R < NN) {
                float v = acc[cb][rr] + bb;
                v = (v > 0.f) ? v : expm1f(v);
                X3out[(size_t)R * 128 + C] = f2bf(v);
            }
        }
    }
}

// ---------------- fuse2: out = X3@Wself2 + mean(X3)@Wneigh2 + S1@Wsk2 + biases ----------------

__global__ __launch_bounds__(256)
void k_fuse2(const unsigned short* __restrict__ X3, const unsigned short* __restrict__ S1,
             const int* __restrict__ row_start, const int* __restrict__ col_idx,
             const short* __restrict__ WpNeigh2, const short* __restrict__ WpSelf2,
             const short* __restrict__ WpSk2, const float* __restrict__ bconv2,
             const float* __restrict__ bsk2, float* __restrict__ out) {
    __shared__ short sW[16384];
    __shared__ short sX[8192];
    const int t = threadIdx.x, wv = t >> 6, lane = t & 63;
    const int row0 = blockIdx.x * 64;
    const int grp = lane >> 5, gl = lane & 31;

    stage_w128(WpNeigh2, sW, wv, lane);

    // phase A: gather AG2 = mean(X3) rows into sX (bf16 A-frag)
#pragma unroll 1
    for (int k = 0; k < 16; ++k) {
        int node = row0 + wv * 16 + k;
        if (node < NN) {
            int beg = row_start[node], end = row_start[node + 1];
            size_t lo = (size_t)(gl * 4);
            float a0, a1, a2, a3;
            gather4(X3, col_idx, beg, end, grp, lo, a0, a1, a2, a3);
            if (lane < 32) {
                float inv = 1.0f / fmaxf((float)(end - beg), 1.0f);
                int Rl = wv * 16 + k;
                int slot = (gl >> 1) ^ (Rl & 7);
                unsigned* p = (unsigned*)&sX[(Rl * 16 + slot) * 8 + (gl & 1) * 4];
                p[0] = (unsigned)f2bf(a0 * inv) | ((unsigned)f2bf(a1 * inv) << 16);
                p[1] = (unsigned)f2bf(a2 * inv) | ((unsigned)f2bf(a3 * inv) << 16);
            }
        }
    }

    floatx4 acc[8];
#pragma unroll
    for (int cb = 0; cb < 8; ++cb) acc[cb] = (floatx4){0.f, 0.f, 0.f, 0.f};
    drain_barrier();
    mm128(sX, sW, wv, lane, acc);      // AG2 @ Wneigh2

    __syncthreads();
    stage_a64(X3, sX, row0, wv, lane);
    stage_w128(WpSelf2, sW, wv, lane);
    drain_barrier();
    mm128(sX, sW, wv, lane, acc);      // X3 @ Wself2

    __syncthreads();
    stage_a64(S1, sX, row0, wv, lane);
    stage_w128(WpSk2, sW, wv, lane);
    drain_barrier();
    mm128(sX, sW, wv, lane, acc);      // S1 @ Wsk2

    // epilogue: + bconv2 + bsk2 -> f32 out (write-only)
    const int m = lane & 15, g = lane >> 4;
    const int rowbase = row0 + wv * 16 + g * 4;
#pragma unroll
    for (int cb = 0; cb < 8; ++cb) {
        int C = cb * 16 + m;
        float bb = bconv2[C] + bsk2[C];
#pragma unroll
        for (int rr = 0; rr < 4; ++rr) {
            int R = rowbase + rr;
            if (R < NN) out[(size_t)R * 128 + C] = acc[cb][rr] + bb;
        }
    }
}

// ---------------- launch ----------------

extern "C" void kernel_launch(void* const* d_in, const int* in_sizes, int n_in,
                              void* d_out, int out_size, void* d_ws, size_t ws_size,
                              hipStream_t stream) {
    const float* h        = (const float*)d_in[0];
    const int*   src      = (const int*)d_in[1];
    const int*   dst      = (const int*)d_in[2];
    const float* W_skip1  = (const float*)d_in[3];
    const float* b_skip1  = (const float*)d_in[4];
    const float* W_skip2  = (const float*)d_in[5];
    const float* b_skip2  = (const float*)d_in[6];
    const float* W_self1  = (const float*)d_in[7];
    const float* W_neigh1 = (const float*)d_in[8];
    const float* b_conv1  = (const float*)d_in[9];
    const float* W_si1    = (const float*)d_in[10];
    const float* b_si1    = (const float*)d_in[11];
    const float* W_si2    = (const float*)d_in[12];
    const float* b_si2    = (const float*)d_in[13];
    const float* W_self2  = (const float*)d_in[14];
    const float* W_neigh2 = (const float*)d_in[15];
    const float* b_conv2  = (const float*)d_in[16];
    float* out = (float*)d_out;

    char* ws = (char*)d_ws;
    int* bcnt      = (int*)ws;            // [128]
    int* gcur      = bcnt + 128;          // [128]
    int* bstart    = bcnt + 256;          // [129]
    int* row_start = bcnt + 100096;       // [50001]
    int* col_idx   = bcnt + 150272;       // [800000] -> ends at byte 3801088
    short* wpk          = (short*)(ws + 3801088);            // 8 x 16384 bf16
    unsigned short* hB  = (unsigned short*)(ws + 4063232);   // h -> X3
    unsigned short* B1  = (unsigned short*)(ws + 16863232);  // T1
    unsigned short* B2  = (unsigned short*)(ws + 29663232);  // S1
    int* bsrc           = (int*)(ws + 42463232);             // [800000]
    int* bdst           = (int*)(ws + 45663232);             // [800000]
    unsigned short* C1s = (unsigned short*)d_out;            // C1 bf16 scratch (dead before fuse2)

    hipMemsetAsync(ws, 0, 128 * sizeof(int), stream);

    // cvt | bucket-count | packW
    k_prep<<<3125 + NBB + 8, 256, 0, stream>>>(h, hB, dst, bcnt,
                                               W_skip1, W_skip2, W_self1, W_neigh1,
                                               W_si1, W_si2, W_self2, W_neigh2, wpk);
    k_bscan<<<1, NB, 0, stream>>>(bcnt, gcur, bstart);

    // LDS-chunked bucketize
    k_bucket<<<NBB, 256, 0, stream>>>(src, dst, gcur, bsrc, bdst);

    // per-bucket scatter+CSR || triple-GEMM (T1, C1, S1)
    k_mega1<<<NB + NT, 256, 0, stream>>>(bsrc, bdst, bstart, row_start, col_idx,
                                         hB, wpk, b_skip1, B1, C1s, B2);

    // fuse1: gather(T1)+C1 -> X1(LDS) -> si1 -> si2 -> X3 (into hB)
    k_fuse1<<<NRT, 256, 0, stream>>>(B1, row_start, col_idx, C1s, b_conv1,
                                     wpk + 4 * 16384, wpk + 5 * 16384,
                                     b_si1, b_si2, hB);

    // fuse2: gather(X3) + X3@Wself2 + S1@Wsk2 -> f32 out (write-only)
    k_fuse2<<<NRT, 256, 0, stream>>>(hB, B2, row_start, col_idx,
                                     wpk + 7 * 16384, wpk + 6 * 16384, wpk + 1 * 16384,
                                     b_conv2, b_skip2, out);
}

// Round 16
// 184.374 us; speedup vs baseline: 1.6599x; 1.6599x over previous
//
#include <hip/hip_runtime.h>
#include <math.h>

#define NN 50000
#define NE 800000
#define NRT 782          // row tiles of 64
#define NT  (NRT * 2)    // x2 col-halves = 1564 blocks per GEMM
#define NB  128          // coarse dst-buckets
#define NPB2 391         // nodes per bucket
#define EPB 2048         // edges per bucketize block
#define NBB 391          // bucketize blocks

typedef __attribute__((ext_vector_type(8))) short short8;
typedef __attribute__((ext_vector_type(4))) float floatx4;

#define AS1 __attribute__((address_space(1)))
#define AS3 __attribute__((address_space(3)))

__device__ __forceinline__ unsigned short f2bf(float f) {
    unsigned u = __float_as_uint(f);
    unsigned r = (u + 0x7fff + ((u >> 16) & 1)) >> 16;
    return (unsigned short)r;
}
__device__ __forceinline__ float bf2f(unsigned short h) {
    return __uint_as_float(((unsigned)h) << 16);
}

// ---------------- prep: cvt (h->bf16) | bucket-count | packW ----------------

__global__ __launch_bounds__(256)
void k_prep(const float* __restrict__ h, unsigned short* __restrict__ hB,
            const int* __restrict__ dst, int* __restrict__ bcnt,
            const float* w0, const float* w1, const float* w2, const float* w3,
            const float* w4, const float* w5, const float* w6, const float* w7,
            short* __restrict__ wpk) {
    int bid = blockIdx.x;
    const int t = threadIdx.x;
    if (bid < 3125) {              // cvt
        int i = (bid * 256 + t) * 8;
        float4 a = *(const float4*)&h[i];
        float4 b = *(const float4*)&h[i + 4];
        short8 v;
        v[0] = (short)f2bf(a.x); v[1] = (short)f2bf(a.y);
        v[2] = (short)f2bf(a.z); v[3] = (short)f2bf(a.w);
        v[4] = (short)f2bf(b.x); v[5] = (short)f2bf(b.y);
        v[6] = (short)f2bf(b.z); v[7] = (short)f2bf(b.w);
        *(short8*)&hB[i] = v;
    } else if (bid < 3125 + NBB) { // bucket-count
        __shared__ int cnt[NB];
        if (t < NB) cnt[t] = 0;
        __syncthreads();
        int base = (bid - 3125) * EPB;
#pragma unroll
        for (int i = 0; i < 8; ++i) {
            int idx = base + i * 256 + t;
            if (idx < NE) atomicAdd(&cnt[dst[idx] / NPB2], 1);
        }
        __syncthreads();
        if (t < NB && cnt[t]) atomicAdd(&bcnt[t], cnt[t]);
    } else {                       // packW, 8 blocks
        int wb = bid - 3125 - NBB;
        const float* W;
        switch (wb) {
            case 0: W = w0; break; case 1: W = w1; break;
            case 2: W = w2; break; case 3: W = w3; break;
            case 4: W = w4; break; case 5: W = w5; break;
            case 6: W = w6; break; default: W = w7; break;
        }
        short* dstp = wpk + (size_t)wb * 16384;
#pragma unroll
        for (int i = 0; i < 8; ++i) {
            int q = t + i * 256;
            int cb = q >> 8, ks = (q >> 6) & 3, lane = q & 63;
            int n = lane & 15, g = lane >> 4;
            int col = cb * 16 + n, krow = ks * 32 + g * 8;
            short8 v;
#pragma unroll
            for (int j = 0; j < 8; ++j)
                v[j] = (short)f2bf(W[(krow + j) * 128 + col]);
            *(short8*)&dstp[q * 8] = v;
        }
    }
}

// ---------------- bscan ----------------

__global__ void k_bscan(const int* __restrict__ bcnt, int* __restrict__ gcur,
                        int* __restrict__ bstart) {
    __shared__ int s[NB];
    int t = threadIdx.x;
    int c = bcnt[t];
    s[t] = c;
    __syncthreads();
    for (int off = 1; off < NB; off <<= 1) {
        int v = (t >= off) ? s[t - off] : 0;
        __syncthreads();
        s[t] += v;
        __syncthreads();
    }
    int excl = s[t] - c;
    gcur[t] = excl;
    bstart[t] = excl;
    if (t == NB - 1) bstart[NB] = s[NB - 1];
}

// ---------------- bucketize ----------------

__global__ __launch_bounds__(256)
void k_bucket(const int* __restrict__ src, const int* __restrict__ dst,
              int* __restrict__ gcur, int* __restrict__ bsrc, int* __restrict__ bdst) {
    __shared__ int psrc[EPB];
    __shared__ int pdst[EPB];
    __shared__ int cnt[NB];
    __shared__ int ebase[NB];
    __shared__ int gbase[NB];
    const int t = threadIdx.x;
    const int e0 = blockIdx.x * EPB;
    const int M = (e0 + EPB <= NE) ? EPB : (NE - e0);

    if (t < NB) cnt[t] = 0;
    __syncthreads();

    int es[8], ed[8], rank[8];
#pragma unroll
    for (int i = 0; i < 8; ++i) {
        int idx = i * 256 + t;
        if (idx < M) {
            es[i] = src[e0 + idx];
            ed[i] = dst[e0 + idx];
            rank[i] = atomicAdd(&cnt[ed[i] / NPB2], 1);
        }
    }
    __syncthreads();
    if (t < NB) ebase[t] = cnt[t];
    __syncthreads();
    for (int off = 1; off < NB; off <<= 1) {
        int v = 0;
        if (t < NB && t >= off) v = ebase[t - off];
        __syncthreads();
        if (t < NB) ebase[t] += v;
        __syncthreads();
    }
    if (t < NB) ebase[t] -= cnt[t];
    __syncthreads();
#pragma unroll
    for (int i = 0; i < 8; ++i) {
        int idx = i * 256 + t;
        if (idx < M) {
            int b = ed[i] / NPB2;
            int pos = ebase[b] + rank[i];
            psrc[pos] = es[i];
            pdst[pos] = ed[i];
        }
    }
    if (t < NB && cnt[t] > 0) gbase[t] = atomicAdd(&gcur[t], cnt[t]);
    __syncthreads();
#pragma unroll
    for (int i = 0; i < 8; ++i) {
        int idx = i * 256 + t;
        if (idx < M) {
            int d = pdst[idx];
            int b = d / NPB2;
            int gpos = gbase[b] + (idx - ebase[b]);
            bsrc[gpos] = psrc[idx];
            bdst[gpos] = d;
        }
    }
}

// ---------------- GEMM body: 64x64 tile, 4 waves, wave = 16 rows ----------------

template<int DOELU, int OUTF32, int NOBIAS>
__device__ __forceinline__ void gemm_body(
        int bid, const unsigned short* __restrict__ A,
        const short* __restrict__ Wp, const float* __restrict__ bias,
        void* outv, short* sW, short* sA) {
    const int t = threadIdx.x;
    const int wv = t >> 6, lane = t & 63;
    const int rb = bid >> 1, ct = bid & 1;
    const int row0 = rb * 64, col0 = ct * 64;
    const int m = lane & 15, g = lane >> 4;

    floatx4 acc[4];
#pragma unroll
    for (int cb = 0; cb < 4; ++cb) acc[cb] = (floatx4){0.f, 0.f, 0.f, 0.f};

    const short* Wc = Wp + ct * 8192;
#pragma unroll
    for (int i = 0; i < 4; ++i) {
        int cbase = (i * 4 + wv) * 64;
        __builtin_amdgcn_global_load_lds(
            (const AS1 unsigned int*)(Wc + (size_t)(cbase + lane) * 8),
            (AS3 unsigned int*)(sW + cbase * 8), 16, 0, 0);
    }
#pragma unroll
    for (int i = 0; i < 4; ++i) {
        int cbase = (i * 4 + wv) * 64;
        int id = cbase + lane;
        int r = id >> 4, cs = id & 15;
        int rg = row0 + r; if (rg >= NN) rg = NN - 1;
        int csrc = cs ^ (r & 7);
        __builtin_amdgcn_global_load_lds(
            (const AS1 unsigned int*)(A + (size_t)rg * 128 + csrc * 8),
            (AS3 unsigned int*)(sA + cbase * 8), 16, 0, 0);
    }
    asm volatile("s_waitcnt vmcnt(0)" ::: "memory");
    __builtin_amdgcn_sched_barrier(0);
    __syncthreads();

    const int r0 = wv * 16;
#pragma unroll
    for (int ks = 0; ks < 4; ++ks) {
        int cxor = (ks * 4 + g) ^ (m & 7);
        short8 af = *(const short8*)&sA[((r0 + m) * 16 + cxor) * 8];
#pragma unroll
        for (int cb = 0; cb < 4; ++cb) {
            short8 bf = *(const short8*)&sW[((cb * 4 + ks) * 64 + lane) * 8];
            acc[cb] = __builtin_amdgcn_mfma_f32_16x16x32_bf16(af, bf, acc[cb], 0, 0, 0);
        }
    }

    const int rowbase = row0 + wv * 16 + g * 4;
#pragma unroll
    for (int cb = 0; cb < 4; ++cb) {
        int C = col0 + cb * 16 + m;
        float bb = NOBIAS ? 0.f : bias[C];
#pragma unroll
        for (int rr = 0; rr < 4; ++rr) {
            int R = rowbase + rr;
            if (R < NN) {
                size_t idx = (size_t)R * 128 + C;
                float v = acc[cb][rr] + bb;
                if (DOELU) v = (v > 0.f) ? v : expm1f(v);
                if (OUTF32) ((float*)outv)[idx] = v;
                else        ((unsigned short*)outv)[idx] = f2bf(v);
            }
        }
    }
}

template<int DOELU, int OUTF32, int NOBIAS>
__global__ __launch_bounds__(256)
void k_mm(const unsigned short* __restrict__ A, const short* __restrict__ Wp,
          const float* __restrict__ bias, void* outv) {
    __shared__ short sMem[16384];
    gemm_body<DOELU, OUTF32, NOBIAS>(blockIdx.x, A, Wp, bias, outv, sMem, sMem + 8192);
}

// ---------------- triple-GEMM (T1, C1, S1): A staged once ----------------

__device__ __forceinline__ void gemm3_body(
        int bid, const unsigned short* __restrict__ A,
        const short* __restrict__ Wn, const short* __restrict__ Ws,
        const short* __restrict__ Wk, const float* __restrict__ bsk1,
        unsigned short* __restrict__ T1, unsigned short* __restrict__ C1,
        unsigned short* __restrict__ S1, short* sW, short* sA) {
    const int t = threadIdx.x;
    const int wv = t >> 6, lane = t & 63;
    const int rb = bid >> 1, ct = bid & 1;
    const int row0 = rb * 64, col0 = ct * 64;
    const int m = lane & 15, g = lane >> 4;

#pragma unroll
    for (int i = 0; i < 4; ++i) {
        int cbase = (i * 4 + wv) * 64;
        int id = cbase + lane;
        int r = id >> 4, cs = id & 15;
        int rg = row0 + r; if (rg >= NN) rg = NN - 1;
        int csrc = cs ^ (r & 7);
        __builtin_amdgcn_global_load_lds(
            (const AS1 unsigned int*)(A + (size_t)rg * 128 + csrc * 8),
            (AS3 unsigned int*)(sA + cbase * 8), 16, 0, 0);
    }

#pragma unroll
    for (int ph = 0; ph < 3; ++ph) {
        if (ph) __syncthreads();
        const short* Wc = (ph == 0 ? Wn : ph == 1 ? Ws : Wk) + ct * 8192;
#pragma unroll
        for (int i = 0; i < 4; ++i) {
            int cbase = (i * 4 + wv) * 64;
            __builtin_amdgcn_global_load_lds(
                (const AS1 unsigned int*)(Wc + (size_t)(cbase + lane) * 8),
                (AS3 unsigned int*)(sW + cbase * 8), 16, 0, 0);
        }
        asm volatile("s_waitcnt vmcnt(0)" ::: "memory");
        __builtin_amdgcn_sched_barrier(0);
        __syncthreads();

        floatx4 acc[4];
#pragma unroll
        for (int cb = 0; cb < 4; ++cb) acc[cb] = (floatx4){0.f, 0.f, 0.f, 0.f};
        const int r0 = wv * 16;
#pragma unroll
        for (int ks = 0; ks < 4; ++ks) {
            int cxor = (ks * 4 + g) ^ (m & 7);
            short8 af = *(const short8*)&sA[((r0 + m) * 16 + cxor) * 8];
#pragma unroll
            for (int cb = 0; cb < 4; ++cb) {
                short8 bf = *(const short8*)&sW[((cb * 4 + ks) * 64 + lane) * 8];
                acc[cb] = __builtin_amdgcn_mfma_f32_16x16x32_bf16(af, bf, acc[cb], 0, 0, 0);
            }
        }

        const int rowbase = row0 + wv * 16 + g * 4;
#pragma unroll
        for (int cb = 0; cb < 4; ++cb) {
            int C = col0 + cb * 16 + m;
            float bb = (ph == 2) ? bsk1[C] : 0.f;
#pragma unroll
            for (int rr = 0; rr < 4; ++rr) {
                int R = rowbase + rr;
                if (R < NN) {
                    size_t idx = (size_t)R * 128 + C;
                    float v = acc[cb][rr] + bb;
                    if (ph == 0)      T1[idx] = f2bf(v);
                    else if (ph == 1) C1[idx] = f2bf(v);
                    else {
                        v = (v > 0.f) ? v : expm1f(v);
                        S1[idx] = f2bf(v);
                    }
                }
            }
        }
    }
}

// ---------------- quad-A GEMM: out = X3@Ws2 + AG2@Wn2 + S1@Wk2 + biases (f32) ----------------

__global__ __launch_bounds__(256)
void k_gfinal(const unsigned short* __restrict__ X3, const unsigned short* __restrict__ AG2,
              const unsigned short* __restrict__ S1, const short* __restrict__ wpk,
              const float* __restrict__ bconv2, const float* __restrict__ bsk2,
              float* __restrict__ out) {
    __shared__ short sMem[16384];
    short* sW = sMem;
    short* sA = sMem + 8192;
    const int t = threadIdx.x;
    const int wv = t >> 6, lane = t & 63;
    const int rb = blockIdx.x >> 1, ct = blockIdx.x & 1;
    const int row0 = rb * 64, col0 = ct * 64;
    const int m = lane & 15, g = lane >> 4;

    floatx4 acc[4];
#pragma unroll
    for (int cb = 0; cb < 4; ++cb) acc[cb] = (floatx4){0.f, 0.f, 0.f, 0.f};

#pragma unroll
    for (int ph = 0; ph < 3; ++ph) {
        if (ph) __syncthreads();
        const unsigned short* Ac = (ph == 0) ? X3 : (ph == 1) ? AG2 : S1;
        const short* Wc = wpk + (ph == 0 ? 6 : ph == 1 ? 7 : 1) * 16384 + ct * 8192;
#pragma unroll
        for (int i = 0; i < 4; ++i) {
            int cbase = (i * 4 + wv) * 64;
            __builtin_amdgcn_global_load_lds(
                (const AS1 unsigned int*)(Wc + (size_t)(cbase + lane) * 8),
                (AS3 unsigned int*)(sW + cbase * 8), 16, 0, 0);
        }
#pragma unroll
        for (int i = 0; i < 4; ++i) {
            int cbase = (i * 4 + wv) * 64;
            int id = cbase + lane;
            int r = id >> 4, cs = id & 15;
            int rg = row0 + r; if (rg >= NN) rg = NN - 1;
            int csrc = cs ^ (r & 7);
            __builtin_amdgcn_global_load_lds(
                (const AS1 unsigned int*)(Ac + (size_t)rg * 128 + csrc * 8),
                (AS3 unsigned int*)(sA + cbase * 8), 16, 0, 0);
        }
        asm volatile("s_waitcnt vmcnt(0)" ::: "memory");
        __builtin_amdgcn_sched_barrier(0);
        __syncthreads();

        const int r0 = wv * 16;
#pragma unroll
        for (int ks = 0; ks < 4; ++ks) {
            int cxor = (ks * 4 + g) ^ (m & 7);
            short8 af = *(const short8*)&sA[((r0 + m) * 16 + cxor) * 8];
#pragma unroll
            for (int cb = 0; cb < 4; ++cb) {
                short8 bf = *(const short8*)&sW[((cb * 4 + ks) * 64 + lane) * 8];
                acc[cb] = __builtin_amdgcn_mfma_f32_16x16x32_bf16(af, bf, acc[cb], 0, 0, 0);
            }
        }
    }

    const int rowbase = row0 + wv * 16 + g * 4;
#pragma unroll
    for (int cb = 0; cb < 4; ++cb) {
        int C = col0 + cb * 16 + m;
        float bb = bconv2[C] + bsk2[C];
#pragma unroll
        for (int rr = 0; rr < 4; ++rr) {
            int R = rowbase + rr;
            if (R < NN) out[(size_t)R * 128 + C] = acc[cb][rr] + bb;
        }
    }
}

// ---------------- mega1: per-bucket scatter+CSR || triple-GEMM ----------------

__global__ __launch_bounds__(256)
void k_mega1(const int* __restrict__ bsrc, const int* __restrict__ bdst,
             const int* __restrict__ bstart, int* __restrict__ row_start,
             int* __restrict__ col_idx,
             const unsigned short* __restrict__ hB, const short* __restrict__ wpk,
             const float* __restrict__ bsk1,
             unsigned short* __restrict__ T1out, unsigned short* __restrict__ C1out,
             unsigned short* __restrict__ S1out) {
    __shared__ short sMem[16384];
    int bid = blockIdx.x;
    if (bid < NB) {
        int* lcur = (int*)sMem;
        int* sc   = lcur + NPB2;
        int* rs   = sc + 512;
        const int t = threadIdx.x;
        const int n0 = bid * NPB2;
        const int n1 = (n0 + NPB2 < NN) ? n0 + NPB2 : NN;
        const int nn = n1 - n0;
        const int w0 = bstart[bid], w1 = bstart[bid + 1];
        for (int i = t; i < nn; i += 256) lcur[i] = 0;
        __syncthreads();
        for (int e = w0 + t; e < w1; e += 256)
            atomicAdd(&lcur[bdst[e] - n0], 1);
        __syncthreads();
        int v0 = (t < nn) ? lcur[t] : 0;
        int v1 = (t + 256 < nn) ? lcur[t + 256] : 0;
        sc[t] = v0; sc[t + 256] = v1;
        __syncthreads();
        for (int off = 1; off < 512; off <<= 1) {
            int a0 = (t >= off) ? sc[t - off] : 0;
            int a1 = (t + 256 >= off) ? sc[t + 256 - off] : 0;
            __syncthreads();
            sc[t] += a0; sc[t + 256] += a1;
            __syncthreads();
        }
        for (int i = t; i < nn; i += 256) {
            int r = w0 + sc[i] - lcur[i];
            rs[i] = r;
            row_start[n0 + i] = r;
            lcur[i] = 0;
        }
        if (bid == 0 && t == 0) row_start[NN] = NE;
        __syncthreads();
        for (int e = w0 + t; e < w1; e += 256) {
            int d = bdst[e] - n0;
            int slot = atomicAdd(&lcur[d], 1);
            col_idx[rs[d] + slot] = bsrc[e];
        }
    } else {
        gemm3_body(bid - NB, hB, wpk + 3 * 16384 /*neigh1*/, wpk + 2 * 16384 /*self1*/,
                   wpk /*skip1*/, bsk1, T1out, C1out, S1out, sMem, sMem + 8192);
    }
}

// ---------------- agg1x: X1 = ELU(C1 + mean(T1) + bc) (wave per node) ----------------

__global__ __launch_bounds__(256)
void k_agg1x(const unsigned short* __restrict__ T1, const int* __restrict__ row_start,
             const int* __restrict__ col_idx, const unsigned short* __restrict__ C1,
             const float* __restrict__ bc, unsigned short* __restrict__ X1out) {
    int node = (blockIdx.x * 256 + threadIdx.x) >> 6;
    int lane = threadIdx.x & 63;
    if (node >= NN) return;
    const int grp = lane >> 5, gl = lane & 31;
    const int beg = row_start[node], end = row_start[node + 1];
    const size_t lo = (size_t)(gl * 4);
    float a0 = 0.f, a1 = 0.f, a2 = 0.f, a3 = 0.f;
    int j = beg;
#pragma unroll 1
    for (; j + 8 <= end; j += 8) {
        int s[4];
#pragma unroll
        for (int u = 0; u < 4; ++u) s[u] = col_idx[j + 2 * u + grp];
        uint2 v[4];
#pragma unroll
        for (int u = 0; u < 4; ++u)
            v[u] = *(const uint2*)&T1[(size_t)s[u] * 128 + lo];
#pragma unroll
        for (int u = 0; u < 4; ++u) {
            a0 += bf2f((unsigned short)(v[u].x & 0xffff));
            a1 += bf2f((unsigned short)(v[u].x >> 16));
            a2 += bf2f((unsigned short)(v[u].y & 0xffff));
            a3 += bf2f((unsigned short)(v[u].y >> 16));
        }
    }
#pragma unroll 1
    for (; j < end; j += 2) {
        int e = j + grp;
        if (e < end) {
            int s = col_idx[e];
            uint2 v = *(const uint2*)&T1[(size_t)s * 128 + lo];
            a0 += bf2f((unsigned short)(v.x & 0xffff));
            a1 += bf2f((unsigned short)(v.x >> 16));
            a2 += bf2f((unsigned short)(v.y & 0xffff));
            a3 += bf2f((unsigned short)(v.y >> 16));
        }
    }
    a0 += __shfl_xor(a0, 32);
    a1 += __shfl_xor(a1, 32);
    a2 += __shfl_xor(a2, 32);
    a3 += __shfl_xor(a3, 32);
    if (lane < 32) {
        float inv = 1.0f / fmaxf((float)(end - beg), 1.0f);
        uint2 c = *(const uint2*)&C1[(size_t)node * 128 + lo];
        float4 bv = *(const float4*)&bc[gl * 4];
        float x0 = a0 * inv + bf2f((unsigned short)(c.x & 0xffff)) + bv.x;
        float x1 = a1 * inv + bf2f((unsigned short)(c.x >> 16)) + bv.y;
        float x2 = a2 * inv + bf2f((unsigned short)(c.y & 0xffff)) + bv.z;
        float x3 = a3 * inv + bf2f((unsigned short)(c.y >> 16)) + bv.w;
        x0 = (x0 > 0.f) ? x0 : expm1f(x0);
        x1 = (x1 > 0.f) ? x1 : expm1f(x1);
        x2 = (x2 > 0.f) ? x2 : expm1f(x2);
        x3 = (x3 > 0.f) ? x3 : expm1f(x3);
        uint2 o;
        o.x = (unsigned)f2bf(x0) | ((unsigned)f2bf(x1) << 16);
        o.y = (unsigned)f2bf(x2) | ((unsigned)f2bf(x3) << 16);
        *(uint2*)&X1out[(size_t)node * 128 + lo] = o;
    }
}

// ---------------- agg2: AG2 = mean(X3), bf16 out (wave per node) ----------------

__global__ __launch_bounds__(256)
void k_agg2(const unsigned short* __restrict__ X3, const int* __restrict__ row_start,
            const int* __restrict__ col_idx, unsigned short* __restrict__ AG2out) {
    int node = (blockIdx.x * 256 + threadIdx.x) >> 6;
    int lane = threadIdx.x & 63;
    if (node >= NN) return;
    const int grp = lane >> 5, gl = lane & 31;
    const int beg = row_start[node], end = row_start[node + 1];
    const size_t lo = (size_t)(gl * 4);
    float a0 = 0.f, a1 = 0.f, a2 = 0.f, a3 = 0.f;
    int j = beg;
#pragma unroll 1
    for (; j + 8 <= end; j += 8) {
        int s[4];
#pragma unroll
        for (int u = 0; u < 4; ++u) s[u] = col_idx[j + 2 * u + grp];
        uint2 v[4];
#pragma unroll
        for (int u = 0; u < 4; ++u)
            v[u] = *(const uint2*)&X3[(size_t)s[u] * 128 + lo];
#pragma unroll
        for (int u = 0; u < 4; ++u) {
            a0 += bf2f((unsigned short)(v[u].x & 0xffff));
            a1 += bf2f((unsigned short)(v[u].x >> 16));
            a2 += bf2f((unsigned short)(v[u].y & 0xffff));
            a3 += bf2f((unsigned short)(v[u].y >> 16));
        }
    }
#pragma unroll 1
    for (; j < end; j += 2) {
        int e = j + grp;
        if (e < end) {
            int s = col_idx[e];
            uint2 v = *(const uint2*)&X3[(size_t)s * 128 + lo];
            a0 += bf2f((unsigned short)(v.x & 0xffff));
            a1 += bf2f((unsigned short)(v.x >> 16));
            a2 += bf2f((unsigned short)(v.y & 0xffff));
            a3 += bf2f((unsigned short)(v.y >> 16));
        }
    }
    a0 += __shfl_xor(a0, 32);
    a1 += __shfl_xor(a1, 32);
    a2 += __shfl_xor(a2, 32);
    a3 += __shfl_xor(a3, 32);
    if (lane < 32) {
        float inv = 1.0f / fmaxf((float)(end - beg), 1.0f);
        uint2 o;
        o.x = (unsigned)f2bf(a0 * inv) | ((unsigned)f2bf(a1 * inv) << 16);
        o.y = (unsigned)f2bf(a2 * inv) | ((unsigned)f2bf(a3 * inv) << 16);
        *(uint2*)&AG2out[(size_t)node * 128 + lo] = o;
    }
}

// ---------------- launch ----------------

extern "C" void kernel_launch(void* const* d_in, const int* in_sizes, int n_in,
                              void* d_out, int out_size, void* d_ws, size_t ws_size,
                              hipStream_t stream) {
    const float* h        = (const float*)d_in[0];
    const int*   src      = (const int*)d_in[1];
    const int*   dst      = (const int*)d_in[2];
    const float* W_skip1  = (const float*)d_in[3];
    const float* b_skip1  = (const float*)d_in[4];
    const float* W_skip2  = (const float*)d_in[5];
    const float* b_skip2  = (const float*)d_in[6];
    const float* W_self1  = (const float*)d_in[7];
    const float* W_neigh1 = (const float*)d_in[8];
    const float* b_conv1  = (const float*)d_in[9];
    const float* W_si1    = (const float*)d_in[10];
    const float* b_si1    = (const float*)d_in[11];
    const float* W_si2    = (const float*)d_in[12];
    const float* b_si2    = (const float*)d_in[13];
    const float* W_self2  = (const float*)d_in[14];
    const float* W_neigh2 = (const float*)d_in[15];
    const float* b_conv2  = (const float*)d_in[16];
    float* out = (float*)d_out;

    char* ws = (char*)d_ws;
    int* bcnt      = (int*)ws;            // [128]
    int* gcur      = bcnt + 128;          // [128]
    int* bstart    = bcnt + 256;          // [129]
    int* row_start = bcnt + 100096;       // [50001]
    int* col_idx   = bcnt + 150272;       // [800000] -> ends at byte 3801088
    short* wpk          = (short*)(ws + 3801088);            // 8 x 16384 bf16
    unsigned short* hB  = (unsigned short*)(ws + 4063232);   // h -> X1 -> X3
    unsigned short* B1  = (unsigned short*)(ws + 16863232);  // T1 -> Y1 -> AG2
    unsigned short* B2  = (unsigned short*)(ws + 29663232);  // S1
    int* bsrc           = (int*)(ws + 42463232);             // [800000]
    int* bdst           = (int*)(ws + 45663232);             // [800000]
    unsigned short* C1s = (unsigned short*)d_out;            // C1 bf16 scratch (dead before gfinal)

    hipMemsetAsync(ws, 0, 128 * sizeof(int), stream);

    // cvt | bucket-count | packW
    k_prep<<<3125 + NBB + 8, 256, 0, stream>>>(h, hB, dst, bcnt,
                                               W_skip1, W_skip2, W_self1, W_neigh1,
                                               W_si1, W_si2, W_self2, W_neigh2, wpk);
    k_bscan<<<1, NB, 0, stream>>>(bcnt, gcur, bstart);

    // LDS-chunked bucketize
    k_bucket<<<NBB, 256, 0, stream>>>(src, dst, gcur, bsrc, bdst);

    // per-bucket scatter+CSR || triple-GEMM (T1 -> B1, C1 -> C1s, S1 -> B2)
    k_mega1<<<NB + NT, 256, 0, stream>>>(bsrc, bdst, bstart, row_start, col_idx,
                                         hB, wpk, b_skip1, B1, C1s, B2);

    // X1 = ELU(C1 + mean(T1) + bc) -> hB   (wave per node)
    k_agg1x<<<12500, 256, 0, stream>>>(B1, row_start, col_idx, C1s, b_conv1, hB);

    // si1: Y1 = ELU(X1@Wsi1+b) -> B1
    k_mm<1, 0, 0><<<NT, 256, 0, stream>>>(hB, wpk + 4 * 16384, b_si1, B1);
    // si2: X3 = ELU(Y1@Wsi2+b) -> hB
    k_mm<1, 0, 0><<<NT, 256, 0, stream>>>(B1, wpk + 5 * 16384, b_si2, hB);

    // AG2 = mean(X3) -> B1 (bf16, wave per node)
    k_agg2<<<12500, 256, 0, stream>>>(hB, row_start, col_idx, B1);

    // out = X3@Wself2 + AG2@Wneigh2 + S1@Wsk2 + (bconv2+bsk2), write-once f32
    k_gfinal<<<NT, 256, 0, stream>>>(hB, B1, B2, wpk, b_conv2, b_skip2, out);
}

// Round 17
// 182.358 us; speedup vs baseline: 1.6782x; 1.0111x over previous
//
#include <hip/hip_runtime.h>
#include <math.h>

#define NN 50000
#define NE 800000
#define NRT 782          // row tiles of 64
#define NT  (NRT * 2)    // x2 col-halves = 1564 blocks per GEMM
#define NB  128          // coarse dst-buckets
#define NPB2 391         // nodes per bucket
#define EPB 2048         // edges per bucketize block
#define NBB 391          // bucketize blocks

typedef __attribute__((ext_vector_type(8))) short short8;
typedef __attribute__((ext_vector_type(4))) float floatx4;

#define AS1 __attribute__((address_space(1)))
#define AS3 __attribute__((address_space(3)))

__device__ __forceinline__ unsigned short f2bf(float f) {
    unsigned u = __float_as_uint(f);
    unsigned r = (u + 0x7fff + ((u >> 16) & 1)) >> 16;
    return (unsigned short)r;
}
__device__ __forceinline__ float bf2f(unsigned short h) {
    return __uint_as_float(((unsigned)h) << 16);
}

// ---------------- prep: cvt (h->bf16) | bucket-count | packW ----------------

__global__ __launch_bounds__(256)
void k_prep(const float* __restrict__ h, unsigned short* __restrict__ hB,
            const int* __restrict__ dst, int* __restrict__ bcnt,
            const float* w0, const float* w1, const float* w2, const float* w3,
            const float* w4, const float* w5, const float* w6, const float* w7,
            short* __restrict__ wpk) {
    int bid = blockIdx.x;
    const int t = threadIdx.x;
    if (bid < 3125) {              // cvt
        int i = (bid * 256 + t) * 8;
        float4 a = *(const float4*)&h[i];
        float4 b = *(const float4*)&h[i + 4];
        short8 v;
        v[0] = (short)f2bf(a.x); v[1] = (short)f2bf(a.y);
        v[2] = (short)f2bf(a.z); v[3] = (short)f2bf(a.w);
        v[4] = (short)f2bf(b.x); v[5] = (short)f2bf(b.y);
        v[6] = (short)f2bf(b.z); v[7] = (short)f2bf(b.w);
        *(short8*)&hB[i] = v;
    } else if (bid < 3125 + NBB) { // bucket-count
        __shared__ int cnt[NB];
        if (t < NB) cnt[t] = 0;
        __syncthreads();
        int base = (bid - 3125) * EPB;
#pragma unroll
        for (int i = 0; i < 8; ++i) {
            int idx = base + i * 256 + t;
            if (idx < NE) atomicAdd(&cnt[dst[idx] / NPB2], 1);
        }
        __syncthreads();
        if (t < NB && cnt[t]) atomicAdd(&bcnt[t], cnt[t]);
    } else {                       // packW, 8 blocks
        int wb = bid - 3125 - NBB;
        const float* W;
        switch (wb) {
            case 0: W = w0; break; case 1: W = w1; break;
            case 2: W = w2; break; case 3: W = w3; break;
            case 4: W = w4; break; case 5: W = w5; break;
            case 6: W = w6; break; default: W = w7; break;
        }
        short* dstp = wpk + (size_t)wb * 16384;
#pragma unroll
        for (int i = 0; i < 8; ++i) {
            int q = t + i * 256;
            int cb = q >> 8, ks = (q >> 6) & 3, lane = q & 63;
            int n = lane & 15, g = lane >> 4;
            int col = cb * 16 + n, krow = ks * 32 + g * 8;
            short8 v;
#pragma unroll
            for (int j = 0; j < 8; ++j)
                v[j] = (short)f2bf(W[(krow + j) * 128 + col]);
            *(short8*)&dstp[q * 8] = v;
        }
    }
}

// ---------------- bscan ----------------

__global__ void k_bscan(const int* __restrict__ bcnt, int* __restrict__ gcur,
                        int* __restrict__ bstart) {
    __shared__ int s[NB];
    int t = threadIdx.x;
    int c = bcnt[t];
    s[t] = c;
    __syncthreads();
    for (int off = 1; off < NB; off <<= 1) {
        int v = (t >= off) ? s[t - off] : 0;
        __syncthreads();
        s[t] += v;
        __syncthreads();
    }
    int excl = s[t] - c;
    gcur[t] = excl;
    bstart[t] = excl;
    if (t == NB - 1) bstart[NB] = s[NB - 1];
}

// ---------------- bucketize ----------------

__global__ __launch_bounds__(256)
void k_bucket(const int* __restrict__ src, const int* __restrict__ dst,
              int* __restrict__ gcur, int* __restrict__ bsrc, int* __restrict__ bdst) {
    __shared__ int psrc[EPB];
    __shared__ int pdst[EPB];
    __shared__ int cnt[NB];
    __shared__ int ebase[NB];
    __shared__ int gbase[NB];
    const int t = threadIdx.x;
    const int e0 = blockIdx.x * EPB;
    const int M = (e0 + EPB <= NE) ? EPB : (NE - e0);

    if (t < NB) cnt[t] = 0;
    __syncthreads();

    int es[8], ed[8], rank[8];
#pragma unroll
    for (int i = 0; i < 8; ++i) {
        int idx = i * 256 + t;
        if (idx < M) {
            es[i] = src[e0 + idx];
            ed[i] = dst[e0 + idx];
            rank[i] = atomicAdd(&cnt[ed[i] / NPB2], 1);
        }
    }
    __syncthreads();
    if (t < NB) ebase[t] = cnt[t];
    __syncthreads();
    for (int off = 1; off < NB; off <<= 1) {
        int v = 0;
        if (t < NB && t >= off) v = ebase[t - off];
        __syncthreads();
        if (t < NB) ebase[t] += v;
        __syncthreads();
    }
    if (t < NB) ebase[t] -= cnt[t];
    __syncthreads();
#pragma unroll
    for (int i = 0; i < 8; ++i) {
        int idx = i * 256 + t;
        if (idx < M) {
            int b = ed[i] / NPB2;
            int pos = ebase[b] + rank[i];
            psrc[pos] = es[i];
            pdst[pos] = ed[i];
        }
    }
    if (t < NB && cnt[t] > 0) gbase[t] = atomicAdd(&gcur[t], cnt[t]);
    __syncthreads();
#pragma unroll
    for (int i = 0; i < 8; ++i) {
        int idx = i * 256 + t;
        if (idx < M) {
            int d = pdst[idx];
            int b = d / NPB2;
            int gpos = gbase[b] + (idx - ebase[b]);
            bsrc[gpos] = psrc[idx];
            bdst[gpos] = d;
        }
    }
}

// ---------------- GEMM body: 64x64 tile, 4 waves, wave = 16 rows ----------------

template<int DOELU, int OUTF32, int NOBIAS>
__device__ __forceinline__ void gemm_body(
        int bid, const unsigned short* __restrict__ A,
        const short* __restrict__ Wp, const float* __restrict__ bias,
        void* outv, short* sW, short* sA) {
    const int t = threadIdx.x;
    const int wv = t >> 6, lane = t & 63;
    const int rb = bid >> 1, ct = bid & 1;
    const int row0 = rb * 64, col0 = ct * 64;
    const int m = lane & 15, g = lane >> 4;

    floatx4 acc[4];
#pragma unroll
    for (int cb = 0; cb < 4; ++cb) acc[cb] = (floatx4){0.f, 0.f, 0.f, 0.f};

    const short* Wc = Wp + ct * 8192;
#pragma unroll
    for (int i = 0; i < 4; ++i) {
        int cbase = (i * 4 + wv) * 64;
        __builtin_amdgcn_global_load_lds(
            (const AS1 unsigned int*)(Wc + (size_t)(cbase + lane) * 8),
            (AS3 unsigned int*)(sW + cbase * 8), 16, 0, 0);
    }
#pragma unroll
    for (int i = 0; i < 4; ++i) {
        int cbase = (i * 4 + wv) * 64;
        int id = cbase + lane;
        int r = id >> 4, cs = id & 15;
        int rg = row0 + r; if (rg >= NN) rg = NN - 1;
        int csrc = cs ^ (r & 7);
        __builtin_amdgcn_global_load_lds(
            (const AS1 unsigned int*)(A + (size_t)rg * 128 + csrc * 8),
            (AS3 unsigned int*)(sA + cbase * 8), 16, 0, 0);
    }
    asm volatile("s_waitcnt vmcnt(0)" ::: "memory");
    __builtin_amdgcn_sched_barrier(0);
    __syncthreads();

    const int r0 = wv * 16;
#pragma unroll
    for (int ks = 0; ks < 4; ++ks) {
        int cxor = (ks * 4 + g) ^ (m & 7);
        short8 af = *(const short8*)&sA[((r0 + m) * 16 + cxor) * 8];
#pragma unroll
        for (int cb = 0; cb < 4; ++cb) {
            short8 bf = *(const short8*)&sW[((cb * 4 + ks) * 64 + lane) * 8];
            acc[cb] = __builtin_amdgcn_mfma_f32_16x16x32_bf16(af, bf, acc[cb], 0, 0, 0);
        }
    }

    const int rowbase = row0 + wv * 16 + g * 4;
#pragma unroll
    for (int cb = 0; cb < 4; ++cb) {
        int C = col0 + cb * 16 + m;
        float bb = NOBIAS ? 0.f : bias[C];
#pragma unroll
        for (int rr = 0; rr < 4; ++rr) {
            int R = rowbase + rr;
            if (R < NN) {
                size_t idx = (size_t)R * 128 + C;
                float v = acc[cb][rr] + bb;
                if (DOELU) v = (v > 0.f) ? v : expm1f(v);
                if (OUTF32) ((float*)outv)[idx] = v;
                else        ((unsigned short*)outv)[idx] = f2bf(v);
            }
        }
    }
}

template<int DOELU, int OUTF32, int NOBIAS>
__global__ __launch_bounds__(256)
void k_mm(const unsigned short* __restrict__ A, const short* __restrict__ Wp,
          const float* __restrict__ bias, void* outv) {
    __shared__ short sMem[16384];
    gemm_body<DOELU, OUTF32, NOBIAS>(blockIdx.x, A, Wp, bias, outv, sMem, sMem + 8192);
}

// ---------------- triple-GEMM (T1, C1, S1): A staged once ----------------

__device__ __forceinline__ void gemm3_body(
        int bid, const unsigned short* __restrict__ A,
        const short* __restrict__ Wn, const short* __restrict__ Ws,
        const short* __restrict__ Wk, const float* __restrict__ bsk1,
        unsigned short* __restrict__ T1, unsigned short* __restrict__ C1,
        unsigned short* __restrict__ S1, short* sW, short* sA) {
    const int t = threadIdx.x;
    const int wv = t >> 6, lane = t & 63;
    const int rb = bid >> 1, ct = bid & 1;
    const int row0 = rb * 64, col0 = ct * 64;
    const int m = lane & 15, g = lane >> 4;

#pragma unroll
    for (int i = 0; i < 4; ++i) {
        int cbase = (i * 4 + wv) * 64;
        int id = cbase + lane;
        int r = id >> 4, cs = id & 15;
        int rg = row0 + r; if (rg >= NN) rg = NN - 1;
        int csrc = cs ^ (r & 7);
        __builtin_amdgcn_global_load_lds(
            (const AS1 unsigned int*)(A + (size_t)rg * 128 + csrc * 8),
            (AS3 unsigned int*)(sA + cbase * 8), 16, 0, 0);
    }

#pragma unroll
    for (int ph = 0; ph < 3; ++ph) {
        if (ph) __syncthreads();
        const short* Wc = (ph == 0 ? Wn : ph == 1 ? Ws : Wk) + ct * 8192;
#pragma unroll
        for (int i = 0; i < 4; ++i) {
            int cbase = (i * 4 + wv) * 64;
            __builtin_amdgcn_global_load_lds(
                (const AS1 unsigned int*)(Wc + (size_t)(cbase + lane) * 8),
                (AS3 unsigned int*)(sW + cbase * 8), 16, 0, 0);
        }
        asm volatile("s_waitcnt vmcnt(0)" ::: "memory");
        __builtin_amdgcn_sched_barrier(0);
        __syncthreads();

        floatx4 acc[4];
#pragma unroll
        for (int cb = 0; cb < 4; ++cb) acc[cb] = (floatx4){0.f, 0.f, 0.f, 0.f};
        const int r0 = wv * 16;
#pragma unroll
        for (int ks = 0; ks < 4; ++ks) {
            int cxor = (ks * 4 + g) ^ (m & 7);
            short8 af = *(const short8*)&sA[((r0 + m) * 16 + cxor) * 8];
#pragma unroll
            for (int cb = 0; cb < 4; ++cb) {
                short8 bf = *(const short8*)&sW[((cb * 4 + ks) * 64 + lane) * 8];
                acc[cb] = __builtin_amdgcn_mfma_f32_16x16x32_bf16(af, bf, acc[cb], 0, 0, 0);
            }
        }

        const int rowbase = row0 + wv * 16 + g * 4;
#pragma unroll
        for (int cb = 0; cb < 4; ++cb) {
            int C = col0 + cb * 16 + m;
            float bb = (ph == 2) ? bsk1[C] : 0.f;
#pragma unroll
            for (int rr = 0; rr < 4; ++rr) {
                int R = rowbase + rr;
                if (R < NN) {
                    size_t idx = (size_t)R * 128 + C;
                    float v = acc[cb][rr] + bb;
                    if (ph == 0)      T1[idx] = f2bf(v);
                    else if (ph == 1) C1[idx] = f2bf(v);
                    else {
                        v = (v > 0.f) ? v : expm1f(v);
                        S1[idx] = f2bf(v);
                    }
                }
            }
        }
    }
}

// ---------------- quad-A GEMM: out = X3@Ws2 + AG2@Wn2 + S1@Wk2 + biases (f32) ----------------

__global__ __launch_bounds__(256)
void k_gfinal(const unsigned short* __restrict__ X3, const unsigned short* __restrict__ AG2,
              const unsigned short* __restrict__ S1, const short* __restrict__ wpk,
              const float* __restrict__ bconv2, const float* __restrict__ bsk2,
              float* __restrict__ out) {
    __shared__ short sMem[16384];
    short* sW = sMem;
    short* sA = sMem + 8192;
    const int t = threadIdx.x;
    const int wv = t >> 6, lane = t & 63;
    const int rb = blockIdx.x >> 1, ct = blockIdx.x & 1;
    const int row0 = rb * 64, col0 = ct * 64;
    const int m = lane & 15, g = lane >> 4;

    floatx4 acc[4];
#pragma unroll
    for (int cb = 0; cb < 4; ++cb) acc[cb] = (floatx4){0.f, 0.f, 0.f, 0.f};

#pragma unroll
    for (int ph = 0; ph < 3; ++ph) {
        if (ph) __syncthreads();
        const unsigned short* Ac = (ph == 0) ? X3 : (ph == 1) ? AG2 : S1;
        const short* Wc = wpk + (ph == 0 ? 6 : ph == 1 ? 7 : 1) * 16384 + ct * 8192;
#pragma unroll
        for (int i = 0; i < 4; ++i) {
            int cbase = (i * 4 + wv) * 64;
            __builtin_amdgcn_global_load_lds(
                (const AS1 unsigned int*)(Wc + (size_t)(cbase + lane) * 8),
                (AS3 unsigned int*)(sW + cbase * 8), 16, 0, 0);
        }
#pragma unroll
        for (int i = 0; i < 4; ++i) {
            int cbase = (i * 4 + wv) * 64;
            int id = cbase + lane;
            int r = id >> 4, cs = id & 15;
            int rg = row0 + r; if (rg >= NN) rg = NN - 1;
            int csrc = cs ^ (r & 7);
            __builtin_amdgcn_global_load_lds(
                (const AS1 unsigned int*)(Ac + (size_t)rg * 128 + csrc * 8),
                (AS3 unsigned int*)(sA + cbase * 8), 16, 0, 0);
        }
        asm volatile("s_waitcnt vmcnt(0)" ::: "memory");
        __builtin_amdgcn_sched_barrier(0);
        __syncthreads();

        const int r0 = wv * 16;
#pragma unroll
        for (int ks = 0; ks < 4; ++ks) {
            int cxor = (ks * 4 + g) ^ (m & 7);
            short8 af = *(const short8*)&sA[((r0 + m) * 16 + cxor) * 8];
#pragma unroll
            for (int cb = 0; cb < 4; ++cb) {
                short8 bf = *(const short8*)&sW[((cb * 4 + ks) * 64 + lane) * 8];
                acc[cb] = __builtin_amdgcn_mfma_f32_16x16x32_bf16(af, bf, acc[cb], 0, 0, 0);
            }
        }
    }

    const int rowbase = row0 + wv * 16 + g * 4;
#pragma unroll
    for (int cb = 0; cb < 4; ++cb) {
        int C = col0 + cb * 16 + m;
        float bb = bconv2[C] + bsk2[C];
#pragma unroll
        for (int rr = 0; rr < 4; ++rr) {
            int R = rowbase + rr;
            if (R < NN) out[(size_t)R * 128 + C] = acc[cb][rr] + bb;
        }
    }
}

// ---------------- mega1: per-bucket scatter+CSR || triple-GEMM ----------------

__global__ __launch_bounds__(256)
void k_mega1(const int* __restrict__ bsrc, const int* __restrict__ bdst,
             const int* __restrict__ bstart, int* __restrict__ row_start,
             int* __restrict__ col_idx,
             const unsigned short* __restrict__ hB, const short* __restrict__ wpk,
             const float* __restrict__ bsk1,
             unsigned short* __restrict__ T1out, unsigned short* __restrict__ C1out,
             unsigned short* __restrict__ S1out) {
    __shared__ short sMem[16384];
    int bid = blockIdx.x;
    if (bid < NB) {
        int* lcur = (int*)sMem;
        int* sc   = lcur + NPB2;
        int* rs   = sc + 512;
        const int t = threadIdx.x;
        const int n0 = bid * NPB2;
        const int n1 = (n0 + NPB2 < NN) ? n0 + NPB2 : NN;
        const int nn = n1 - n0;
        const int w0 = bstart[bid], w1 = bstart[bid + 1];
        for (int i = t; i < nn; i += 256) lcur[i] = 0;
        __syncthreads();
        for (int e = w0 + t; e < w1; e += 256)
            atomicAdd(&lcur[bdst[e] - n0], 1);
        __syncthreads();
        int v0 = (t < nn) ? lcur[t] : 0;
        int v1 = (t + 256 < nn) ? lcur[t + 256] : 0;
        sc[t] = v0; sc[t + 256] = v1;
        __syncthreads();
        for (int off = 1; off < 512; off <<= 1) {
            int a0 = (t >= off) ? sc[t - off] : 0;
            int a1 = (t + 256 >= off) ? sc[t + 256 - off] : 0;
            __syncthreads();
            sc[t] += a0; sc[t + 256] += a1;
            __syncthreads();
        }
        for (int i = t; i < nn; i += 256) {
            int r = w0 + sc[i] - lcur[i];
            rs[i] = r;
            row_start[n0 + i] = r;
            lcur[i] = 0;
        }
        if (bid == 0 && t == 0) row_start[NN] = NE;
        __syncthreads();
        for (int e = w0 + t; e < w1; e += 256) {
            int d = bdst[e] - n0;
            int slot = atomicAdd(&lcur[d], 1);
            col_idx[rs[d] + slot] = bsrc[e];
        }
    } else {
        gemm3_body(bid - NB, hB, wpk + 3 * 16384 /*neigh1*/, wpk + 2 * 16384 /*self1*/,
                   wpk /*skip1*/, bsk1, T1out, C1out, S1out, sMem, sMem + 8192);
    }
}

// ---------------- gather8: 4-edge groups, 16B/lane; result on lanes<16 (8 cols each) ----------------

__device__ __forceinline__ void gather8(const unsigned short* __restrict__ F,
                                        const int* __restrict__ col_idx,
                                        int beg, int end, int grp, size_t lo,
                                        float a[8]) {
#pragma unroll
    for (int i = 0; i < 8; ++i) a[i] = 0.f;
    int j = beg;
#pragma unroll 1
    for (; j + 16 <= end; j += 16) {
        int s[4];
#pragma unroll
        for (int u = 0; u < 4; ++u) s[u] = col_idx[j + 4 * u + grp];
        uint4 v[4];
#pragma unroll
        for (int u = 0; u < 4; ++u)
            v[u] = *(const uint4*)&F[(size_t)s[u] * 128 + lo];
#pragma unroll
        for (int u = 0; u < 4; ++u) {
            a[0] += bf2f((unsigned short)(v[u].x & 0xffff));
            a[1] += bf2f((unsigned short)(v[u].x >> 16));
            a[2] += bf2f((unsigned short)(v[u].y & 0xffff));
            a[3] += bf2f((unsigned short)(v[u].y >> 16));
            a[4] += bf2f((unsigned short)(v[u].z & 0xffff));
            a[5] += bf2f((unsigned short)(v[u].z >> 16));
            a[6] += bf2f((unsigned short)(v[u].w & 0xffff));
            a[7] += bf2f((unsigned short)(v[u].w >> 16));
        }
    }
#pragma unroll 1
    for (; j < end; j += 4) {
        int e = j + grp;
        if (e < end) {
            int s = col_idx[e];
            uint4 v = *(const uint4*)&F[(size_t)s * 128 + lo];
            a[0] += bf2f((unsigned short)(v.x & 0xffff));
            a[1] += bf2f((unsigned short)(v.x >> 16));
            a[2] += bf2f((unsigned short)(v.y & 0xffff));
            a[3] += bf2f((unsigned short)(v.y >> 16));
            a[4] += bf2f((unsigned short)(v.z & 0xffff));
            a[5] += bf2f((unsigned short)(v.z >> 16));
            a[6] += bf2f((unsigned short)(v.w & 0xffff));
            a[7] += bf2f((unsigned short)(v.w >> 16));
        }
    }
#pragma unroll
    for (int i = 0; i < 8; ++i) {
        a[i] += __shfl_xor(a[i], 16);
        a[i] += __shfl_xor(a[i], 32);
    }
}

// ---------------- agg1x: X1 = ELU(C1 + mean(T1) + bc) (wave per node) ----------------

__global__ __launch_bounds__(256)
void k_agg1x(const unsigned short* __restrict__ T1, const int* __restrict__ row_start,
             const int* __restrict__ col_idx, const unsigned short* __restrict__ C1,
             const float* __restrict__ bc, unsigned short* __restrict__ X1out) {
    int node = (blockIdx.x * 256 + threadIdx.x) >> 6;
    int lane = threadIdx.x & 63;
    if (node >= NN) return;
    const int grp = lane >> 4, gl = lane & 15;
    const int beg = row_start[node], end = row_start[node + 1];
    const size_t lo = (size_t)(gl * 8);
    float a[8];
    gather8(T1, col_idx, beg, end, grp, lo, a);
    if (lane < 16) {
        float inv = 1.0f / fmaxf((float)(end - beg), 1.0f);
        uint4 c = *(const uint4*)&C1[(size_t)node * 128 + lo];
        float4 b0 = *(const float4*)&bc[gl * 8];
        float4 b1 = *(const float4*)&bc[gl * 8 + 4];
        float x[8];
        x[0] = a[0] * inv + bf2f((unsigned short)(c.x & 0xffff)) + b0.x;
        x[1] = a[1] * inv + bf2f((unsigned short)(c.x >> 16)) + b0.y;
        x[2] = a[2] * inv + bf2f((unsigned short)(c.y & 0xffff)) + b0.z;
        x[3] = a[3] * inv + bf2f((unsigned short)(c.y >> 16)) + b0.w;
        x[4] = a[4] * inv + bf2f((unsigned short)(c.z & 0xffff)) + b1.x;
        x[5] = a[5] * inv + bf2f((unsigned short)(c.z >> 16)) + b1.y;
        x[6] = a[6] * inv + bf2f((unsigned short)(c.w & 0xffff)) + b1.z;
        x[7] = a[7] * inv + bf2f((unsigned short)(c.w >> 16)) + b1.w;
#pragma unroll
        for (int i = 0; i < 8; ++i)
            x[i] = (x[i] > 0.f) ? x[i] : expm1f(x[i]);
        uint4 o;
        o.x = (unsigned)f2bf(x[0]) | ((unsigned)f2bf(x[1]) << 16);
        o.y = (unsigned)f2bf(x[2]) | ((unsigned)f2bf(x[3]) << 16);
        o.z = (unsigned)f2bf(x[4]) | ((unsigned)f2bf(x[5]) << 16);
        o.w = (unsigned)f2bf(x[6]) | ((unsigned)f2bf(x[7]) << 16);
        *(uint4*)&X1out[(size_t)node * 128 + lo] = o;
    }
}

// ---------------- agg2: AG2 = mean(X3), bf16 out (wave per node) ----------------

__global__ __launch_bounds__(256)
void k_agg2(const unsigned short* __restrict__ X3, const int* __restrict__ row_start,
            const int* __restrict__ col_idx, unsigned short* __restrict__ AG2out) {
    int node = (blockIdx.x * 256 + threadIdx.x) >> 6;
    int lane = threadIdx.x & 63;
    if (node >= NN) return;
    const int grp = lane >> 4, gl = lane & 15;
    const int beg = row_start[node], end = row_start[node + 1];
    const size_t lo = (size_t)(gl * 8);
    float a[8];
    gather8(X3, col_idx, beg, end, grp, lo, a);
    if (lane < 16) {
        float inv = 1.0f / fmaxf((float)(end - beg), 1.0f);
        uint4 o;
        o.x = (unsigned)f2bf(a[0] * inv) | ((unsigned)f2bf(a[1] * inv) << 16);
        o.y = (unsigned)f2bf(a[2] * inv) | ((unsigned)f2bf(a[3] * inv) << 16);
        o.z = (unsigned)f2bf(a[4] * inv) | ((unsigned)f2bf(a[5] * inv) << 16);
        o.w = (unsigned)f2bf(a[6] * inv) | ((unsigned)f2bf(a[7] * inv) << 16);
        *(uint4*)&AG2out[(size_t)node * 128 + lo] = o;
    }
}

// ---------------- launch ----------------

extern "C" void kernel_launch(void* const* d_in, const int* in_sizes, int n_in,
                              void* d_out, int out_size, void* d_ws, size_t ws_size,
                              hipStream_t stream) {
    const float* h        = (const float*)d_in[0];
    const int*   src      = (const int*)d_in[1];
    const int*   dst      = (const int*)d_in[2];
    const float* W_skip1  = (const float*)d_in[3];
    const float* b_skip1  = (const float*)d_in[4];
    const float* W_skip2  = (const float*)d_in[5];
    const float* b_skip2  = (const float*)d_in[6];
    const float* W_self1  = (const float*)d_in[7];
    const float* W_neigh1 = (const float*)d_in[8];
    const float* b_conv1  = (const float*)d_in[9];
    const float* W_si1    = (const float*)d_in[10];
    const float* b_si1    = (const float*)d_in[11];
    const float* W_si2    = (const float*)d_in[12];
    const float* b_si2    = (const float*)d_in[13];
    const float* W_self2  = (const float*)d_in[14];
    const float* W_neigh2 = (const float*)d_in[15];
    const float* b_conv2  = (const float*)d_in[16];
    float* out = (float*)d_out;

    char* ws = (char*)d_ws;
    int* bcnt      = (int*)ws;            // [128]
    int* gcur      = bcnt + 128;          // [128]
    int* bstart    = bcnt + 256;          // [129]
    int* row_start = bcnt + 100096;       // [50001]
    int* col_idx   = bcnt + 150272;       // [800000] -> ends at byte 3801088
    short* wpk          = (short*)(ws + 3801088);            // 8 x 16384 bf16
    unsigned short* hB  = (unsigned short*)(ws + 4063232);   // h -> X1 -> X3
    unsigned short* B1  = (unsigned short*)(ws + 16863232);  // T1 -> Y1 -> AG2
    unsigned short* B2  = (unsigned short*)(ws + 29663232);  // S1
    int* bsrc           = (int*)(ws + 42463232);             // [800000]
    int* bdst           = (int*)(ws + 45663232);             // [800000]
    unsigned short* C1s = (unsigned short*)d_out;            // C1 bf16 scratch (dead before gfinal)

    hipMemsetAsync(ws, 0, 128 * sizeof(int), stream);

    // cvt | bucket-count | packW
    k_prep<<<3125 + NBB + 8, 256, 0, stream>>>(h, hB, dst, bcnt,
                                               W_skip1, W_skip2, W_self1, W_neigh1,
                                               W_si1, W_si2, W_self2, W_neigh2, wpk);
    k_bscan<<<1, NB, 0, stream>>>(bcnt, gcur, bstart);

    // LDS-chunked bucketize
    k_bucket<<<NBB, 256, 0, stream>>>(src, dst, gcur, bsrc, bdst);

    // per-bucket scatter+CSR || triple-GEMM (T1 -> B1, C1 -> C1s, S1 -> B2)
    k_mega1<<<NB + NT, 256, 0, stream>>>(bsrc, bdst, bstart, row_start, col_idx,
                                         hB, wpk, b_skip1, B1, C1s, B2);

    // X1 = ELU(C1 + mean(T1) + bc) -> hB   (wave per node)
    k_agg1x<<<12500, 256, 0, stream>>>(B1, row_start, col_idx, C1s, b_conv1, hB);

    // si1: Y1 = ELU(X1@Wsi1+b) -> B1
    k_mm<1, 0, 0><<<NT, 256, 0, stream>>>(hB, wpk + 4 * 16384, b_si1, B1);
    // si2: X3 = ELU(Y1@Wsi2+b) -> hB
    k_mm<1, 0, 0><<<NT, 256, 0, stream>>>(B1, wpk + 5 * 16384, b_si2, hB);

    // AG2 = mean(X3) -> B1 (bf16, wave per node)
    k_agg2<<<12500, 256, 0, stream>>>(hB, row_start, col_idx, B1);

    // out = X3@Wself2 + AG2@Wneigh2 + S1@Wsk2 + (bconv2+bsk2), write-once f32
    k_gfinal<<<NT, 256, 0, stream>>>(hB, B1, B2, wpk, b_conv2, b_skip2, out);
}

// Round 18
// 177.272 us; speedup vs baseline: 1.7264x; 1.0287x over previous
//
#include <hip/hip_runtime.h>
#include <math.h>

#define NN 50000
#define NE 800000
#define NRT 782          // row tiles of 64
#define NT  (NRT * 2)    // x2 col-halves = 1564 blocks per GEMM
#define NB  256          // coarse dst-buckets
#define NPB2 196         // nodes per bucket (256*196 = 50176 >= NN)
#define EPB 2048         // edges per bucketize block
#define NBB 391          // bucketize blocks

typedef __attribute__((ext_vector_type(8))) short short8;
typedef __attribute__((ext_vector_type(4))) float floatx4;

#define AS1 __attribute__((address_space(1)))
#define AS3 __attribute__((address_space(3)))

__device__ __forceinline__ unsigned short f2bf(float f) {
    unsigned u = __float_as_uint(f);
    unsigned r = (u + 0x7fff + ((u >> 16) & 1)) >> 16;
    return (unsigned short)r;
}
__device__ __forceinline__ float bf2f(unsigned short h) {
    return __uint_as_float(((unsigned)h) << 16);
}

// ---------------- prep: cvt (h->bf16) | bucket-count | packW ----------------

__global__ __launch_bounds__(256)
void k_prep(const float* __restrict__ h, unsigned short* __restrict__ hB,
            const int* __restrict__ dst, int* __restrict__ bcnt,
            const float* w0, const float* w1, const float* w2, const float* w3,
            const float* w4, const float* w5, const float* w6, const float* w7,
            short* __restrict__ wpk) {
    int bid = blockIdx.x;
    const int t = threadIdx.x;
    if (bid < 3125) {              // cvt
        int i = (bid * 256 + t) * 8;
        float4 a = *(const float4*)&h[i];
        float4 b = *(const float4*)&h[i + 4];
        short8 v;
        v[0] = (short)f2bf(a.x); v[1] = (short)f2bf(a.y);
        v[2] = (short)f2bf(a.z); v[3] = (short)f2bf(a.w);
        v[4] = (short)f2bf(b.x); v[5] = (short)f2bf(b.y);
        v[6] = (short)f2bf(b.z); v[7] = (short)f2bf(b.w);
        *(short8*)&hB[i] = v;
    } else if (bid < 3125 + NBB) { // bucket-count
        __shared__ int cnt[NB];
        cnt[t] = 0;
        __syncthreads();
        int base = (bid - 3125) * EPB;
#pragma unroll
        for (int i = 0; i < 8; ++i) {
            int idx = base + i * 256 + t;
            if (idx < NE) atomicAdd(&cnt[dst[idx] / NPB2], 1);
        }
        __syncthreads();
        if (cnt[t]) atomicAdd(&bcnt[t], cnt[t]);
    } else {                       // packW, 8 blocks
        int wb = bid - 3125 - NBB;
        const float* W;
        switch (wb) {
            case 0: W = w0; break; case 1: W = w1; break;
            case 2: W = w2; break; case 3: W = w3; break;
            case 4: W = w4; break; case 5: W = w5; break;
            case 6: W = w6; break; default: W = w7; break;
        }
        short* dstp = wpk + (size_t)wb * 16384;
#pragma unroll
        for (int i = 0; i < 8; ++i) {
            int q = t + i * 256;
            int cb = q >> 8, ks = (q >> 6) & 3, lane = q & 63;
            int n = lane & 15, g = lane >> 4;
            int col = cb * 16 + n, krow = ks * 32 + g * 8;
            short8 v;
#pragma unroll
            for (int j = 0; j < 8; ++j)
                v[j] = (short)f2bf(W[(krow + j) * 128 + col]);
            *(short8*)&dstp[q * 8] = v;
        }
    }
}

// ---------------- bscan: 256-wide prefix -> gcur + bstart ----------------

__global__ void k_bscan(const int* __restrict__ bcnt, int* __restrict__ gcur,
                        int* __restrict__ bstart) {
    __shared__ int s[NB];
    int t = threadIdx.x;
    int c = bcnt[t];
    s[t] = c;
    __syncthreads();
    for (int off = 1; off < NB; off <<= 1) {
        int v = (t >= off) ? s[t - off] : 0;
        __syncthreads();
        s[t] += v;
        __syncthreads();
    }
    int excl = s[t] - c;
    gcur[t] = excl;
    bstart[t] = excl;
    if (t == NB - 1) bstart[NB] = s[NB - 1];
}

// ---------------- bucketize ----------------

__global__ __launch_bounds__(256)
void k_bucket(const int* __restrict__ src, const int* __restrict__ dst,
              int* __restrict__ gcur, int* __restrict__ bsrc, int* __restrict__ bdst) {
    __shared__ int psrc[EPB];
    __shared__ int pdst[EPB];
    __shared__ int cnt[NB];
    __shared__ int ebase[NB];
    __shared__ int gbase[NB];
    const int t = threadIdx.x;
    const int e0 = blockIdx.x * EPB;
    const int M = (e0 + EPB <= NE) ? EPB : (NE - e0);

    cnt[t] = 0;
    __syncthreads();

    int es[8], ed[8], rank[8];
#pragma unroll
    for (int i = 0; i < 8; ++i) {
        int idx = i * 256 + t;
        if (idx < M) {
            es[i] = src[e0 + idx];
            ed[i] = dst[e0 + idx];
            rank[i] = atomicAdd(&cnt[ed[i] / NPB2], 1);
        }
    }
    __syncthreads();
    ebase[t] = cnt[t];
    __syncthreads();
    for (int off = 1; off < NB; off <<= 1) {
        int v = (t >= off) ? ebase[t - off] : 0;
        __syncthreads();
        ebase[t] += v;
        __syncthreads();
    }
    ebase[t] -= cnt[t];   // exclusive
    __syncthreads();
#pragma unroll
    for (int i = 0; i < 8; ++i) {
        int idx = i * 256 + t;
        if (idx < M) {
            int b = ed[i] / NPB2;
            int pos = ebase[b] + rank[i];
            psrc[pos] = es[i];
            pdst[pos] = ed[i];
        }
    }
    if (cnt[t] > 0) gbase[t] = atomicAdd(&gcur[t], cnt[t]);
    __syncthreads();
#pragma unroll
    for (int i = 0; i < 8; ++i) {
        int idx = i * 256 + t;
        if (idx < M) {
            int d = pdst[idx];
            int b = d / NPB2;
            int gpos = gbase[b] + (idx - ebase[b]);
            bsrc[gpos] = psrc[idx];
            bdst[gpos] = d;
        }
    }
}

// ---------------- shared GEMM helpers ----------------

__device__ __forceinline__ void drain_barrier() {
    asm volatile("s_waitcnt vmcnt(0)" ::: "memory");
    __builtin_amdgcn_sched_barrier(0);
    __syncthreads();
}

__device__ __forceinline__ void stage_w128(const short* Wc, short* sW, int wv, int lane) {
#pragma unroll
    for (int i = 0; i < 8; ++i) {
        int cbase = (i * 4 + wv) * 64;
        __builtin_amdgcn_global_load_lds(
            (const AS1 unsigned int*)(Wc + (size_t)(cbase + lane) * 8),
            (AS3 unsigned int*)(sW + cbase * 8), 16, 0, 0);
    }
}

__device__ __forceinline__ void stage_a64(const unsigned short* Ac, short* sX, int row0,
                                          int wv, int lane) {
#pragma unroll
    for (int i = 0; i < 4; ++i) {
        int cbase = (i * 4 + wv) * 64;
        int id = cbase + lane;
        int r = id >> 4, cs = id & 15;
        int rg = row0 + r; if (rg >= NN) rg = NN - 1;
        int csrc = cs ^ (r & 7);
        __builtin_amdgcn_global_load_lds(
            (const AS1 unsigned int*)(Ac + (size_t)rg * 128 + csrc * 8),
            (AS3 unsigned int*)(sX + cbase * 8), 16, 0, 0);
    }
}

// 64 rows x 128 cols MFMA pass; wave wv owns rows wv*16..+15
__device__ __forceinline__ void mm128(const short* sX, const short* sW, int wv, int lane,
                                      floatx4 acc[8]) {
    const int m = lane & 15, g = lane >> 4;
    const int r0 = wv * 16;
#pragma unroll
    for (int ks = 0; ks < 4; ++ks) {
        int slot = (ks * 4 + g) ^ (m & 7);
        short8 af = *(const short8*)&sX[((r0 + m) * 16 + slot) * 8];
#pragma unroll
        for (int cb = 0; cb < 8; ++cb) {
            short8 bf = *(const short8*)&sW[((cb * 4 + ks) * 64 + lane) * 8];
            acc[cb] = __builtin_amdgcn_mfma_f32_16x16x32_bf16(af, bf, acc[cb], 0, 0, 0);
        }
    }
}

// bias+ELU on acc -> bf16 into sX (A-frag layout, wave-local rows); zero acc
__device__ __forceinline__ void act_to_lds64(short* sX, const float* bias, int wv, int lane,
                                             floatx4 acc[8]) {
    const int m = lane & 15, g = lane >> 4;
#pragma unroll
    for (int cb = 0; cb < 8; ++cb) {
        int C = cb * 16 + m;
        float bb = bias[C];
#pragma unroll
        for (int rr = 0; rr < 4; ++rr) {
            int Rl = wv * 16 + g * 4 + rr;
            float v = acc[cb][rr] + bb;
            v = (v > 0.f) ? v : expm1f(v);
            int slot = (C >> 3) ^ (Rl & 7);
            sX[(Rl * 16 + slot) * 8 + (C & 7)] = (short)f2bf(v);
        }
    }
#pragma unroll
    for (int cb = 0; cb < 8; ++cb) acc[cb] = (floatx4){0.f, 0.f, 0.f, 0.f};
}

// ---------------- triple-GEMM (T1, C1, S1): A staged once ----------------

__device__ __forceinline__ void gemm3_body(
        int bid, const unsigned short* __restrict__ A,
        const short* __restrict__ Wn, const short* __restrict__ Ws,
        const short* __restrict__ Wk, const float* __restrict__ bsk1,
        unsigned short* __restrict__ T1, unsigned short* __restrict__ C1,
        unsigned short* __restrict__ S1, short* sW, short* sA) {
    const int t = threadIdx.x;
    const int wv = t >> 6, lane = t & 63;
    const int rb = bid >> 1, ct = bid & 1;
    const int row0 = rb * 64, col0 = ct * 64;
    const int m = lane & 15, g = lane >> 4;

#pragma unroll
    for (int i = 0; i < 4; ++i) {
        int cbase = (i * 4 + wv) * 64;
        int id = cbase + lane;
        int r = id >> 4, cs = id & 15;
        int rg = row0 + r; if (rg >= NN) rg = NN - 1;
        int csrc = cs ^ (r & 7);
        __builtin_amdgcn_global_load_lds(
            (const AS1 unsigned int*)(A + (size_t)rg * 128 + csrc * 8),
            (AS3 unsigned int*)(sA + cbase * 8), 16, 0, 0);
    }

#pragma unroll
    for (int ph = 0; ph < 3; ++ph) {
        if (ph) __syncthreads();
        const short* Wc = (ph == 0 ? Wn : ph == 1 ? Ws : Wk) + ct * 8192;
#pragma unroll
        for (int i = 0; i < 4; ++i) {
            int cbase = (i * 4 + wv) * 64;
            __builtin_amdgcn_global_load_lds(
                (const AS1 unsigned int*)(Wc + (size_t)(cbase + lane) * 8),
                (AS3 unsigned int*)(sW + cbase * 8), 16, 0, 0);
        }
        asm volatile("s_waitcnt vmcnt(0)" ::: "memory");
        __builtin_amdgcn_sched_barrier(0);
        __syncthreads();

        floatx4 acc[4];
#pragma unroll
        for (int cb = 0; cb < 4; ++cb) acc[cb] = (floatx4){0.f, 0.f, 0.f, 0.f};
        const int r0 = wv * 16;
#pragma unroll
        for (int ks = 0; ks < 4; ++ks) {
            int cxor = (ks * 4 + g) ^ (m & 7);
            short8 af = *(const short8*)&sA[((r0 + m) * 16 + cxor) * 8];
#pragma unroll
            for (int cb = 0; cb < 4; ++cb) {
                short8 bf = *(const short8*)&sW[((cb * 4 + ks) * 64 + lane) * 8];
                acc[cb] = __builtin_amdgcn_mfma_f32_16x16x32_bf16(af, bf, acc[cb], 0, 0, 0);
            }
        }

        const int rowbase = row0 + wv * 16 + g * 4;
#pragma unroll
        for (int cb = 0; cb < 4; ++cb) {
            int C = col0 + cb * 16 + m;
            float bb = (ph == 2) ? bsk1[C] : 0.f;
#pragma unroll
            for (int rr = 0; rr < 4; ++rr) {
                int R = rowbase + rr;
                if (R < NN) {
                    size_t idx = (size_t)R * 128 + C;
                    float v = acc[cb][rr] + bb;
                    if (ph == 0)      T1[idx] = f2bf(v);
                    else if (ph == 1) C1[idx] = f2bf(v);
                    else {
                        v = (v > 0.f) ? v : expm1f(v);
                        S1[idx] = f2bf(v);
                    }
                }
            }
        }
    }
}

// ---------------- mega1: per-bucket scatter+CSR || triple-GEMM ----------------

__global__ __launch_bounds__(256)
void k_mega1(const int* __restrict__ bsrc, const int* __restrict__ bdst,
             const int* __restrict__ bstart, int* __restrict__ row_start,
             int* __restrict__ col_idx,
             const unsigned short* __restrict__ hB, const short* __restrict__ wpk,
             const float* __restrict__ bsk1,
             unsigned short* __restrict__ T1out, unsigned short* __restrict__ C1out,
             unsigned short* __restrict__ S1out) {
    __shared__ short sMem[16384];
    int bid = blockIdx.x;
    if (bid < NB) {
        int* lcur = (int*)sMem;          // [NPB2]
        int* sc   = lcur + NPB2;         // [512]
        int* rs   = sc + 512;            // [NPB2]
        const int t = threadIdx.x;
        const int n0 = bid * NPB2;
        const int n1 = (n0 + NPB2 < NN) ? n0 + NPB2 : NN;
        const int nn = n1 - n0;
        const int w0 = bstart[bid], w1 = bstart[bid + 1];
        for (int i = t; i < nn; i += 256) lcur[i] = 0;
        __syncthreads();
        for (int e = w0 + t; e < w1; e += 256)
            atomicAdd(&lcur[bdst[e] - n0], 1);
        __syncthreads();
        int v0 = (t < nn) ? lcur[t] : 0;
        int v1 = (t + 256 < nn) ? lcur[t + 256] : 0;
        sc[t] = v0; sc[t + 256] = v1;
        __syncthreads();
        for (int off = 1; off < 512; off <<= 1) {
            int a0 = (t >= off) ? sc[t - off] : 0;
            int a1 = (t + 256 >= off) ? sc[t + 256 - off] : 0;
            __syncthreads();
            sc[t] += a0; sc[t + 256] += a1;
            __syncthreads();
        }
        for (int i = t; i < nn; i += 256) {
            int r = w0 + sc[i] - lcur[i];
            rs[i] = r;
            row_start[n0 + i] = r;
            lcur[i] = 0;
        }
        if (bid == 0 && t == 0) row_start[NN] = NE;
        __syncthreads();
        for (int e = w0 + t; e < w1; e += 256) {
            int d = bdst[e] - n0;
            int slot = atomicAdd(&lcur[d], 1);
            col_idx[rs[d] + slot] = bsrc[e];
        }
    } else {
        gemm3_body(bid - NB, hB, wpk + 3 * 16384 /*neigh1*/, wpk + 2 * 16384 /*self1*/,
                   wpk /*skip1*/, bsk1, T1out, C1out, S1out, sMem, sMem + 8192);
    }
}

// ---------------- quad-A GEMM: out = X3@Ws2 + AG2@Wn2 + S1@Wk2 + biases (f32) ----------------

__global__ __launch_bounds__(256)
void k_gfinal(const unsigned short* __restrict__ X3, const unsigned short* __restrict__ AG2,
              const unsigned short* __restrict__ S1, const short* __restrict__ wpk,
              const float* __restrict__ bconv2, const float* __restrict__ bsk2,
              float* __restrict__ out) {
    __shared__ short sMem[16384];
    short* sW = sMem;
    short* sA = sMem + 8192;
    const int t = threadIdx.x;
    const int wv = t >> 6, lane = t & 63;
    const int rb = blockIdx.x >> 1, ct = blockIdx.x & 1;
    const int row0 = rb * 64, col0 = ct * 64;
    const int m = lane & 15, g = lane >> 4;

    floatx4 acc[4];
#pragma unroll
    for (int cb = 0; cb < 4; ++cb) acc[cb] = (floatx4){0.f, 0.f, 0.f, 0.f};

#pragma unroll
    for (int ph = 0; ph < 3; ++ph) {
        if (ph) __syncthreads();
        const unsigned short* Ac = (ph == 0) ? X3 : (ph == 1) ? AG2 : S1;
        const short* Wc = wpk + (ph == 0 ? 6 : ph == 1 ? 7 : 1) * 16384 + ct * 8192;
#pragma unroll
        for (int i = 0; i < 4; ++i) {
            int cbase = (i * 4 + wv) * 64;
            __builtin_amdgcn_global_load_lds(
                (const AS1 unsigned int*)(Wc + (size_t)(cbase + lane) * 8),
                (AS3 unsigned int*)(sW + cbase * 8), 16, 0, 0);
        }
#pragma unroll
        for (int i = 0; i < 4; ++i) {
            int cbase = (i * 4 + wv) * 64;
            int id = cbase + lane;
            int r = id >> 4, cs = id & 15;
            int rg = row0 + r; if (rg >= NN) rg = NN - 1;
            int csrc = cs ^ (r & 7);
            __builtin_amdgcn_global_load_lds(
                (const AS1 unsigned int*)(Ac + (size_t)rg * 128 + csrc * 8),
                (AS3 unsigned int*)(sA + cbase * 8), 16, 0, 0);
        }
        asm volatile("s_waitcnt vmcnt(0)" ::: "memory");
        __builtin_amdgcn_sched_barrier(0);
        __syncthreads();

        const int r0 = wv * 16;
#pragma unroll
        for (int ks = 0; ks < 4; ++ks) {
            int cxor = (ks * 4 + g) ^ (m & 7);
            short8 af = *(const short8*)&sA[((r0 + m) * 16 + cxor) * 8];
#pragma unroll
            for (int cb = 0; cb < 4; ++cb) {
                short8 bf = *(const short8*)&sW[((cb * 4 + ks) * 64 + lane) * 8];
                acc[cb] = __builtin_amdgcn_mfma_f32_16x16x32_bf16(af, bf, acc[cb], 0, 0, 0);
            }
        }
    }

    const int rowbase = row0 + wv * 16 + g * 4;
#pragma unroll
    for (int cb = 0; cb < 4; ++cb) {
        int C = col0 + cb * 16 + m;
        float bb = bconv2[C] + bsk2[C];
#pragma unroll
        for (int rr = 0; rr < 4; ++rr) {
            int R = rowbase + rr;
            if (R < NN) out[(size_t)R * 128 + C] = acc[cb][rr] + bb;
        }
    }
}

// ---------------- si12: X3 = ELU(ELU(X1@Wsi1+bs1)@Wsi2+bs2), in-place on hB ----------------

__global__ __launch_bounds__(256)
void k_si12(unsigned short* __restrict__ X1io, const short* __restrict__ WpSi1,
            const short* __restrict__ WpSi2, const float* __restrict__ bs1,
            const float* __restrict__ bs2) {
    __shared__ short sW[16384];   // 32 KB
    __shared__ short sX[8192];    // 16 KB
    const int t = threadIdx.x, wv = t >> 6, lane = t & 63;
    const int row0 = blockIdx.x * 64;

    floatx4 acc[8];
#pragma unroll
    for (int cb = 0; cb < 8; ++cb) acc[cb] = (floatx4){0.f, 0.f, 0.f, 0.f};

    stage_a64(X1io, sX, row0, wv, lane);
    stage_w128(WpSi1, sW, wv, lane);
    drain_barrier();
    mm128(sX, sW, wv, lane, acc);        // X1 @ Wsi1

    __syncthreads();                     // all waves done with sW (sX rows are wave-local)
    stage_w128(WpSi2, sW, wv, lane);     // async W2 load overlaps the act VALU below
    act_to_lds64(sX, bs1, wv, lane, acc);  // Y1 -> sX (wave-local rows), acc zeroed
    drain_barrier();
    mm128(sX, sW, wv, lane, acc);        // Y1 @ Wsi2

    const int m = lane & 15, g = lane >> 4;
    const int rowbase = row0 + wv * 16 + g * 4;
#pragma unroll
    for (int cb = 0; cb < 8; ++cb) {
        int C = cb * 16 + m;
        float bb = bs2[C];
#pragma unroll
        for (int rr = 0; rr < 4; ++rr) {
            int R = rowbase + rr;
            if (R < NN) {
                float v = acc[cb][rr] + bb;
                v = (v > 0.f) ? v : expm1f(v);
                X1io[(size_t)R * 128 + C] = f2bf(v);   // in-place: own rows only
            }
        }
    }
}

// ---------------- gather8: 4-edge groups, 16B/lane; result on lanes<16 (8 cols each) ----------------

__device__ __forceinline__ void gather8(const unsigned short* __restrict__ F,
                                        const int* __restrict__ col_idx,
                                        int beg, int end, int grp, size_t lo,
                                        float a[8]) {
#pragma unroll
    for (int i = 0; i < 8; ++i) a[i] = 0.f;
    int j = beg;
#pragma unroll 1
    for (; j + 16 <= end; j += 16) {
        int s[4];
#pragma unroll
        for (int u = 0; u < 4; ++u) s[u] = col_idx[j + 4 * u + grp];
        uint4 v[4];
#pragma unroll
        for (int u = 0; u < 4; ++u)
            v[u] = *(const uint4*)&F[(size_t)s[u] * 128 + lo];
#pragma unroll
        for (int u = 0; u < 4; ++u) {
            a[0] += bf2f((unsigned short)(v[u].x & 0xffff));
            a[1] += bf2f((unsigned short)(v[u].x >> 16));
            a[2] += bf2f((unsigned short)(v[u].y & 0xffff));
            a[3] += bf2f((unsigned short)(v[u].y >> 16));
            a[4] += bf2f((unsigned short)(v[u].z & 0xffff));
            a[5] += bf2f((unsigned short)(v[u].z >> 16));
            a[6] += bf2f((unsigned short)(v[u].w & 0xffff));
            a[7] += bf2f((unsigned short)(v[u].w >> 16));
        }
    }
#pragma unroll 1
    for (; j < end; j += 4) {
        int e = j + grp;
        if (e < end) {
            int s = col_idx[e];
            uint4 v = *(const uint4*)&F[(size_t)s * 128 + lo];
            a[0] += bf2f((unsigned short)(v.x & 0xffff));
            a[1] += bf2f((unsigned short)(v.x >> 16));
            a[2] += bf2f((unsigned short)(v.y & 0xffff));
            a[3] += bf2f((unsigned short)(v.y >> 16));
            a[4] += bf2f((unsigned short)(v.z & 0xffff));
            a[5] += bf2f((unsigned short)(v.z >> 16));
            a[6] += bf2f((unsigned short)(v.w & 0xffff));
            a[7] += bf2f((unsigned short)(v.w >> 16));
        }
    }
#pragma unroll
    for (int i = 0; i < 8; ++i) {
        a[i] += __shfl_xor(a[i], 16);
        a[i] += __shfl_xor(a[i], 32);
    }
}

// ---------------- agg1x: X1 = ELU(C1 + mean(T1) + bc) (wave per node) ----------------

__global__ __launch_bounds__(256)
void k_agg1x(const unsigned short* __restrict__ T1, const int* __restrict__ row_start,
             const int* __restrict__ col_idx, const unsigned short* __restrict__ C1,
             const float* __restrict__ bc, unsigned short* __restrict__ X1out) {
    int node = (blockIdx.x * 256 + threadIdx.x) >> 6;
    int lane = threadIdx.x & 63;
    if (node >= NN) return;
    const int grp = lane >> 4, gl = lane & 15;
    const int beg = row_start[node], end = row_start[node + 1];
    const size_t lo = (size_t)(gl * 8);
    float a[8];
    gather8(T1, col_idx, beg, end, grp, lo, a);
    if (lane < 16) {
        float inv = 1.0f / fmaxf((float)(end - beg), 1.0f);
        uint4 c = *(const uint4*)&C1[(size_t)node * 128 + lo];
        float4 b0 = *(const float4*)&bc[gl * 8];
        float4 b1 = *(const float4*)&bc[gl * 8 + 4];
        float x[8];
        x[0] = a[0] * inv + bf2f((unsigned short)(c.x & 0xffff)) + b0.x;
        x[1] = a[1] * inv + bf2f((unsigned short)(c.x >> 16)) + b0.y;
        x[2] = a[2] * inv + bf2f((unsigned short)(c.y & 0xffff)) + b0.z;
        x[3] = a[3] * inv + bf2f((unsigned short)(c.y >> 16)) + b0.w;
        x[4] = a[4] * inv + bf2f((unsigned short)(c.z & 0xffff)) + b1.x;
        x[5] = a[5] * inv + bf2f((unsigned short)(c.z >> 16)) + b1.y;
        x[6] = a[6] * inv + bf2f((unsigned short)(c.w & 0xffff)) + b1.z;
        x[7] = a[7] * inv + bf2f((unsigned short)(c.w >> 16)) + b1.w;
#pragma unroll
        for (int i = 0; i < 8; ++i)
            x[i] = (x[i] > 0.f) ? x[i] : expm1f(x[i]);
        uint4 o;
        o.x = (unsigned)f2bf(x[0]) | ((unsigned)f2bf(x[1]) << 16);
        o.y = (unsigned)f2bf(x[2]) | ((unsigned)f2bf(x[3]) << 16);
        o.z = (unsigned)f2bf(x[4]) | ((unsigned)f2bf(x[5]) << 16);
        o.w = (unsigned)f2bf(x[6]) | ((unsigned)f2bf(x[7]) << 16);
        *(uint4*)&X1out[(size_t)node * 128 + lo] = o;
    }
}

// ---------------- agg2: AG2 = mean(X3), bf16 out (wave per node) ----------------

__global__ __launch_bounds__(256)
void k_agg2(const unsigned short* __restrict__ X3, const int* __restrict__ row_start,
            const int* __restrict__ col_idx, unsigned short* __restrict__ AG2out) {
    int node = (blockIdx.x * 256 + threadIdx.x) >> 6;
    int lane = threadIdx.x & 63;
    if (node >= NN) return;
    const int grp = lane >> 4, gl = lane & 15;
    const int beg = row_start[node], end = row_start[node + 1];
    const size_t lo = (size_t)(gl * 8);
    float a[8];
    gather8(X3, col_idx, beg, end, grp, lo, a);
    if (lane < 16) {
        float inv = 1.0f / fmaxf((float)(end - beg), 1.0f);
        uint4 o;
        o.x = (unsigned)f2bf(a[0] * inv) | ((unsigned)f2bf(a[1] * inv) << 16);
        o.y = (unsigned)f2bf(a[2] * inv) | ((unsigned)f2bf(a[3] * inv) << 16);
        o.z = (unsigned)f2bf(a[4] * inv) | ((unsigned)f2bf(a[5] * inv) << 16);
        o.w = (unsigned)f2bf(a[6] * inv) | ((unsigned)f2bf(a[7] * inv) << 16);
        *(uint4*)&AG2out[(size_t)node * 128 + lo] = o;
    }
}

// ---------------- launch ----------------

extern "C" void kernel_launch(void* const* d_in, const int* in_sizes, int n_in,
                              void* d_out, int out_size, void* d_ws, size_t ws_size,
                              hipStream_t stream) {
    const float* h        = (const float*)d_in[0];
    const int*   src      = (const int*)d_in[1];
    const int*   dst      = (const int*)d_in[2];
    const float* W_skip1  = (const float*)d_in[3];
    const float* b_skip1  = (const float*)d_in[4];
    const float* W_skip2  = (const float*)d_in[5];
    const float* b_skip2  = (const float*)d_in[6];
    const float* W_self1  = (const float*)d_in[7];
    const float* W_neigh1 = (const float*)d_in[8];
    const float* b_conv1  = (const float*)d_in[9];
    const float* W_si1    = (const float*)d_in[10];
    const float* b_si1    = (const float*)d_in[11];
    const float* W_si2    = (const float*)d_in[12];
    const float* b_si2    = (const float*)d_in[13];
    const float* W_self2  = (const float*)d_in[14];
    const float* W_neigh2 = (const float*)d_in[15];
    const float* b_conv2  = (const float*)d_in[16];
    float* out = (float*)d_out;

    char* ws = (char*)d_ws;
    int* bcnt      = (int*)ws;            // [256]
    int* gcur      = bcnt + 256;          // [256]
    int* bstart    = bcnt + 512;          // [257]
    int* row_start = bcnt + 100096;       // [50001]
    int* col_idx   = bcnt + 150272;       // [800000] -> ends at byte 3801088
    short* wpk          = (short*)(ws + 3801088);            // 8 x 16384 bf16
    unsigned short* hB  = (unsigned short*)(ws + 4063232);   // h -> X1 -> X3
    unsigned short* B1  = (unsigned short*)(ws + 16863232);  // T1 -> AG2
    unsigned short* B2  = (unsigned short*)(ws + 29663232);  // S1
    int* bsrc           = (int*)(ws + 42463232);             // [800000]
    int* bdst           = (int*)(ws + 45663232);             // [800000]
    unsigned short* C1s = (unsigned short*)d_out;            // C1 bf16 scratch (dead before gfinal)

    hipMemsetAsync(ws, 0, 256 * sizeof(int), stream);

    // cvt | bucket-count | packW
    k_prep<<<3125 + NBB + 8, 256, 0, stream>>>(h, hB, dst, bcnt,
                                               W_skip1, W_skip2, W_self1, W_neigh1,
                                               W_si1, W_si2, W_self2, W_neigh2, wpk);
    k_bscan<<<1, NB, 0, stream>>>(bcnt, gcur, bstart);

    // LDS-chunked bucketize
    k_bucket<<<NBB, 256, 0, stream>>>(src, dst, gcur, bsrc, bdst);

    // per-bucket scatter+CSR || triple-GEMM (T1 -> B1, C1 -> C1s, S1 -> B2)
    k_mega1<<<NB + NT, 256, 0, stream>>>(bsrc, bdst, bstart, row_start, col_idx,
                                         hB, wpk, b_skip1, B1, C1s, B2);

    // X1 = ELU(C1 + mean(T1) + bc) -> hB   (wave per node)
    k_agg1x<<<12500, 256, 0, stream>>>(B1, row_start, col_idx, C1s, b_conv1, hB);

    // si1+si2 fused, in-place hB: X3 = ELU(ELU(X1@Wsi1+b)@Wsi2+b)
    k_si12<<<NRT, 256, 0, stream>>>(hB, wpk + 4 * 16384, wpk + 5 * 16384, b_si1, b_si2);

    // AG2 = mean(X3) -> B1 (bf16, wave per node)
    k_agg2<<<12500, 256, 0, stream>>>(hB, row_start, col_idx, B1);

    // out = X3@Wself2 + AG2@Wneigh2 + S1@Wsk2 + (bconv2+bsk2), write-once f32
    k_gfinal<<<NT, 256, 0, stream>>>(hB, B1, B2, wpk, b_conv2, b_skip2, out);
}

// Round 19
// 176.123 us; speedup vs baseline: 1.7377x; 1.0065x over previous
//
#include <hip/hip_runtime.h>
#include <math.h>

#define NN 50000
#define NE 800000
#define NRT 782          // row tiles of 64
#define NT  (NRT * 2)    // x2 col-halves = 1564 blocks per GEMM
#define NB  256          // coarse dst-buckets
#define NPB2 196         // nodes per bucket (256*196 = 50176 >= NN)
#define EPB 2048         // edges per bucketize block
#define NBB 391          // bucketize blocks

typedef __attribute__((ext_vector_type(8))) short short8;
typedef __attribute__((ext_vector_type(4))) float floatx4;

#define AS1 __attribute__((address_space(1)))
#define AS3 __attribute__((address_space(3)))

__device__ __forceinline__ unsigned short f2bf(float f) {
    unsigned u = __float_as_uint(f);
    unsigned r = (u + 0x7fff + ((u >> 16) & 1)) >> 16;
    return (unsigned short)r;
}
__device__ __forceinline__ float bf2f(unsigned short h) {
    return __uint_as_float(((unsigned)h) << 16);
}

// ---------------- prep: cvt (h->bf16) | bucket-count | packW ----------------

__global__ __launch_bounds__(256)
void k_prep(const float* __restrict__ h, unsigned short* __restrict__ hB,
            const int* __restrict__ dst, int* __restrict__ bcnt,
            const float* w0, const float* w1, const float* w2, const float* w3,
            const float* w4, const float* w5, const float* w6, const float* w7,
            short* __restrict__ wpk) {
    int bid = blockIdx.x;
    const int t = threadIdx.x;
    if (bid < 3125) {              // cvt
        int i = (bid * 256 + t) * 8;
        float4 a = *(const float4*)&h[i];
        float4 b = *(const float4*)&h[i + 4];
        short8 v;
        v[0] = (short)f2bf(a.x); v[1] = (short)f2bf(a.y);
        v[2] = (short)f2bf(a.z); v[3] = (short)f2bf(a.w);
        v[4] = (short)f2bf(b.x); v[5] = (short)f2bf(b.y);
        v[6] = (short)f2bf(b.z); v[7] = (short)f2bf(b.w);
        *(short8*)&hB[i] = v;
    } else if (bid < 3125 + NBB) { // bucket-count
        __shared__ int cnt[NB];
        cnt[t] = 0;
        __syncthreads();
        int base = (bid - 3125) * EPB;
#pragma unroll
        for (int i = 0; i < 8; ++i) {
            int idx = base + i * 256 + t;
            if (idx < NE) atomicAdd(&cnt[dst[idx] / NPB2], 1);
        }
        __syncthreads();
        if (cnt[t]) atomicAdd(&bcnt[t], cnt[t]);
    } else {                       // packW, 8 blocks
        int wb = bid - 3125 - NBB;
        const float* W;
        switch (wb) {
            case 0: W = w0; break; case 1: W = w1; break;
            case 2: W = w2; break; case 3: W = w3; break;
            case 4: W = w4; break; case 5: W = w5; break;
            case 6: W = w6; break; default: W = w7; break;
        }
        short* dstp = wpk + (size_t)wb * 16384;
#pragma unroll
        for (int i = 0; i < 8; ++i) {
            int q = t + i * 256;
            int cb = q >> 8, ks = (q >> 6) & 3, lane = q & 63;
            int n = lane & 15, g = lane >> 4;
            int col = cb * 16 + n, krow = ks * 32 + g * 8;
            short8 v;
#pragma unroll
            for (int j = 0; j < 8; ++j)
                v[j] = (short)f2bf(W[(krow + j) * 128 + col]);
            *(short8*)&dstp[q * 8] = v;
        }
    }
}

// ---------------- bscan: 256-wide prefix -> gcur + bstart ----------------

__global__ void k_bscan(const int* __restrict__ bcnt, int* __restrict__ gcur,
                        int* __restrict__ bstart) {
    __shared__ int s[NB];
    int t = threadIdx.x;
    int c = bcnt[t];
    s[t] = c;
    __syncthreads();
    for (int off = 1; off < NB; off <<= 1) {
        int v = (t >= off) ? s[t - off] : 0;
        __syncthreads();
        s[t] += v;
        __syncthreads();
    }
    int excl = s[t] - c;
    gcur[t] = excl;
    bstart[t] = excl;
    if (t == NB - 1) bstart[NB] = s[NB - 1];
}

// ---------------- bucketize ----------------

__global__ __launch_bounds__(256)
void k_bucket(const int* __restrict__ src, const int* __restrict__ dst,
              int* __restrict__ gcur, int* __restrict__ bsrc, int* __restrict__ bdst) {
    __shared__ int psrc[EPB];
    __shared__ int pdst[EPB];
    __shared__ int cnt[NB];
    __shared__ int ebase[NB];
    __shared__ int gbase[NB];
    const int t = threadIdx.x;
    const int e0 = blockIdx.x * EPB;
    const int M = (e0 + EPB <= NE) ? EPB : (NE - e0);

    cnt[t] = 0;
    __syncthreads();

    int es[8], ed[8], rank[8];
#pragma unroll
    for (int i = 0; i < 8; ++i) {
        int idx = i * 256 + t;
        if (idx < M) {
            es[i] = src[e0 + idx];
            ed[i] = dst[e0 + idx];
            rank[i] = atomicAdd(&cnt[ed[i] / NPB2], 1);
        }
    }
    __syncthreads();
    ebase[t] = cnt[t];
    __syncthreads();
    for (int off = 1; off < NB; off <<= 1) {
        int v = (t >= off) ? ebase[t - off] : 0;
        __syncthreads();
        ebase[t] += v;
        __syncthreads();
    }
    ebase[t] -= cnt[t];   // exclusive
    __syncthreads();
#pragma unroll
    for (int i = 0; i < 8; ++i) {
        int idx = i * 256 + t;
        if (idx < M) {
            int b = ed[i] / NPB2;
            int pos = ebase[b] + rank[i];
            psrc[pos] = es[i];
            pdst[pos] = ed[i];
        }
    }
    if (cnt[t] > 0) gbase[t] = atomicAdd(&gcur[t], cnt[t]);
    __syncthreads();
#pragma unroll
    for (int i = 0; i < 8; ++i) {
        int idx = i * 256 + t;
        if (idx < M) {
            int d = pdst[idx];
            int b = d / NPB2;
            int gpos = gbase[b] + (idx - ebase[b]);
            bsrc[gpos] = psrc[idx];
            bdst[gpos] = d;
        }
    }
}

// ---------------- GEMM body: 64x64 tile, 4 waves, wave = 16 rows ----------------

template<int DOELU, int OUTF32, int NOBIAS>
__device__ __forceinline__ void gemm_body(
        int bid, const unsigned short* __restrict__ A,
        const short* __restrict__ Wp, const float* __restrict__ bias,
        void* outv, short* sW, short* sA) {
    const int t = threadIdx.x;
    const int wv = t >> 6, lane = t & 63;
    const int rb = bid >> 1, ct = bid & 1;
    const int row0 = rb * 64, col0 = ct * 64;
    const int m = lane & 15, g = lane >> 4;

    floatx4 acc[4];
#pragma unroll
    for (int cb = 0; cb < 4; ++cb) acc[cb] = (floatx4){0.f, 0.f, 0.f, 0.f};

    const short* Wc = Wp + ct * 8192;
#pragma unroll
    for (int i = 0; i < 4; ++i) {
        int cbase = (i * 4 + wv) * 64;
        __builtin_amdgcn_global_load_lds(
            (const AS1 unsigned int*)(Wc + (size_t)(cbase + lane) * 8),
            (AS3 unsigned int*)(sW + cbase * 8), 16, 0, 0);
    }
#pragma unroll
    for (int i = 0; i < 4; ++i) {
        int cbase = (i * 4 + wv) * 64;
        int id = cbase + lane;
        int r = id >> 4, cs = id & 15;
        int rg = row0 + r; if (rg >= NN) rg = NN - 1;
        int csrc = cs ^ (r & 7);
        __builtin_amdgcn_global_load_lds(
            (const AS1 unsigned int*)(A + (size_t)rg * 128 + csrc * 8),
            (AS3 unsigned int*)(sA + cbase * 8), 16, 0, 0);
    }
    asm volatile("s_waitcnt vmcnt(0)" ::: "memory");
    __builtin_amdgcn_sched_barrier(0);
    __syncthreads();

    const int r0 = wv * 16;
#pragma unroll
    for (int ks = 0; ks < 4; ++ks) {
        int cxor = (ks * 4 + g) ^ (m & 7);
        short8 af = *(const short8*)&sA[((r0 + m) * 16 + cxor) * 8];
#pragma unroll
        for (int cb = 0; cb < 4; ++cb) {
            short8 bf = *(const short8*)&sW[((cb * 4 + ks) * 64 + lane) * 8];
            acc[cb] = __builtin_amdgcn_mfma_f32_16x16x32_bf16(af, bf, acc[cb], 0, 0, 0);
        }
    }

    const int rowbase = row0 + wv * 16 + g * 4;
#pragma unroll
    for (int cb = 0; cb < 4; ++cb) {
        int C = col0 + cb * 16 + m;
        float bb = NOBIAS ? 0.f : bias[C];
#pragma unroll
        for (int rr = 0; rr < 4; ++rr) {
            int R = rowbase + rr;
            if (R < NN) {
                size_t idx = (size_t)R * 128 + C;
                float v = acc[cb][rr] + bb;
                if (DOELU) v = (v > 0.f) ? v : expm1f(v);
                if (OUTF32) ((float*)outv)[idx] = v;
                else        ((unsigned short*)outv)[idx] = f2bf(v);
            }
        }
    }
}

template<int DOELU, int OUTF32, int NOBIAS>
__global__ __launch_bounds__(256)
void k_mm(const unsigned short* __restrict__ A, const short* __restrict__ Wp,
          const float* __restrict__ bias, void* outv) {
    __shared__ short sMem[16384];
    gemm_body<DOELU, OUTF32, NOBIAS>(blockIdx.x, A, Wp, bias, outv, sMem, sMem + 8192);
}

// ---------------- triple-GEMM (T1, C1, S1): A staged once ----------------

__device__ __forceinline__ void gemm3_body(
        int bid, const unsigned short* __restrict__ A,
        const short* __restrict__ Wn, const short* __restrict__ Ws,
        const short* __restrict__ Wk, const float* __restrict__ bsk1,
        unsigned short* __restrict__ T1, unsigned short* __restrict__ C1,
        unsigned short* __restrict__ S1, short* sW, short* sA) {
    const int t = threadIdx.x;
    const int wv = t >> 6, lane = t & 63;
    const int rb = bid >> 1, ct = bid & 1;
    const int row0 = rb * 64, col0 = ct * 64;
    const int m = lane & 15, g = lane >> 4;

#pragma unroll
    for (int i = 0; i < 4; ++i) {
        int cbase = (i * 4 + wv) * 64;
        int id = cbase + lane;
        int r = id >> 4, cs = id & 15;
        int rg = row0 + r; if (rg >= NN) rg = NN - 1;
        int csrc = cs ^ (r & 7);
        __builtin_amdgcn_global_load_lds(
            (const AS1 unsigned int*)(A + (size_t)rg * 128 + csrc * 8),
            (AS3 unsigned int*)(sA + cbase * 8), 16, 0, 0);
    }

#pragma unroll
    for (int ph = 0; ph < 3; ++ph) {
        if (ph) __syncthreads();
        const short* Wc = (ph == 0 ? Wn : ph == 1 ? Ws : Wk) + ct * 8192;
#pragma unroll
        for (int i = 0; i < 4; ++i) {
            int cbase = (i * 4 + wv) * 64;
            __builtin_amdgcn_global_load_lds(
                (const AS1 unsigned int*)(Wc + (size_t)(cbase + lane) * 8),
                (AS3 unsigned int*)(sW + cbase * 8), 16, 0, 0);
        }
        asm volatile("s_waitcnt vmcnt(0)" ::: "memory");
        __builtin_amdgcn_sched_barrier(0);
        __syncthreads();

        floatx4 acc[4];
#pragma unroll
        for (int cb = 0; cb < 4; ++cb) acc[cb] = (floatx4){0.f, 0.f, 0.f, 0.f};
        const int r0 = wv * 16;
#pragma unroll
        for (int ks = 0; ks < 4; ++ks) {
            int cxor = (ks * 4 + g) ^ (m & 7);
            short8 af = *(const short8*)&sA[((r0 + m) * 16 + cxor) * 8];
#pragma unroll
            for (int cb = 0; cb < 4; ++cb) {
                short8 bf = *(const short8*)&sW[((cb * 4 + ks) * 64 + lane) * 8];
                acc[cb] = __builtin_amdgcn_mfma_f32_16x16x32_bf16(af, bf, acc[cb], 0, 0, 0);
            }
        }

        const int rowbase = row0 + wv * 16 + g * 4;
#pragma unroll
        for (int cb = 0; cb < 4; ++cb) {
            int C = col0 + cb * 16 + m;
            float bb = (ph == 2) ? bsk1[C] : 0.f;
#pragma unroll
            for (int rr = 0; rr < 4; ++rr) {
                int R = rowbase + rr;
                if (R < NN) {
                    size_t idx = (size_t)R * 128 + C;
                    float v = acc[cb][rr] + bb;
                    if (ph == 0)      T1[idx] = f2bf(v);
                    else if (ph == 1) C1[idx] = f2bf(v);
                    else {
                        v = (v > 0.f) ? v : expm1f(v);
                        S1[idx] = f2bf(v);
                    }
                }
            }
        }
    }
}

// ---------------- mega1: per-bucket scatter+CSR || triple-GEMM ----------------

__global__ __launch_bounds__(256)
void k_mega1(const int* __restrict__ bsrc, const int* __restrict__ bdst,
             const int* __restrict__ bstart, int* __restrict__ row_start,
             int* __restrict__ col_idx,
             const unsigned short* __restrict__ hB, const short* __restrict__ wpk,
             const float* __restrict__ bsk1,
             unsigned short* __restrict__ T1out, unsigned short* __restrict__ C1out,
             unsigned short* __restrict__ S1out) {
    __shared__ short sMem[16384];
    int bid = blockIdx.x;
    if (bid < NB) {
        int* lcur = (int*)sMem;          // [NPB2]
        int* sc   = lcur + NPB2;         // [512]
        int* rs   = sc + 512;            // [NPB2]
        const int t = threadIdx.x;
        const int n0 = bid * NPB2;
        const int n1 = (n0 + NPB2 < NN) ? n0 + NPB2 : NN;
        const int nn = n1 - n0;
        if (n0 < NN) {
            const int w0 = bstart[bid], w1 = bstart[bid + 1];
            for (int i = t; i < nn; i += 256) lcur[i] = 0;
            __syncthreads();
            for (int e = w0 + t; e < w1; e += 256)
                atomicAdd(&lcur[bdst[e] - n0], 1);
            __syncthreads();
            int v0 = (t < nn) ? lcur[t] : 0;
            int v1 = (t + 256 < nn) ? lcur[t + 256] : 0;
            sc[t] = v0; sc[t + 256] = v1;
            __syncthreads();
            for (int off = 1; off < 512; off <<= 1) {
                int a0 = (t >= off) ? sc[t - off] : 0;
                int a1 = (t + 256 >= off) ? sc[t + 256 - off] : 0;
                __syncthreads();
                sc[t] += a0; sc[t + 256] += a1;
                __syncthreads();
            }
            for (int i = t; i < nn; i += 256) {
                int r = w0 + sc[i] - lcur[i];
                rs[i] = r;
                row_start[n0 + i] = r;
                lcur[i] = 0;
            }
            if (bid == 0 && t == 0) row_start[NN] = NE;
            __syncthreads();
            for (int e = w0 + t; e < w1; e += 256) {
                int d = bdst[e] - n0;
                int slot = atomicAdd(&lcur[d], 1);
                col_idx[rs[d] + slot] = bsrc[e];
            }
        }
    } else {
        gemm3_body(bid - NB, hB, wpk + 3 * 16384 /*neigh1*/, wpk + 2 * 16384 /*self1*/,
                   wpk /*skip1*/, bsk1, T1out, C1out, S1out, sMem, sMem + 8192);
    }
}

// ---------------- quad-A GEMM: out = X3@Ws2 + AG2@Wn2 + S1@Wk2 + biases (f32) ----------------

__global__ __launch_bounds__(256)
void k_gfinal(const unsigned short* __restrict__ X3, const unsigned short* __restrict__ AG2,
              const unsigned short* __restrict__ S1, const short* __restrict__ wpk,
              const float* __restrict__ bconv2, const float* __restrict__ bsk2,
              float* __restrict__ out) {
    __shared__ short sMem[16384];
    short* sW = sMem;
    short* sA = sMem + 8192;
    const int t = threadIdx.x;
    const int wv = t >> 6, lane = t & 63;
    const int rb = blockIdx.x >> 1, ct = blockIdx.x & 1;
    const int row0 = rb * 64, col0 = ct * 64;
    const int m = lane & 15, g = lane >> 4;

    floatx4 acc[4];
#pragma unroll
    for (int cb = 0; cb < 4; ++cb) acc[cb] = (floatx4){0.f, 0.f, 0.f, 0.f};

#pragma unroll
    for (int ph = 0; ph < 3; ++ph) {
        if (ph) __syncthreads();
        const unsigned short* Ac = (ph == 0) ? X3 : (ph == 1) ? AG2 : S1;
        const short* Wc = wpk + (ph == 0 ? 6 : ph == 1 ? 7 : 1) * 16384 + ct * 8192;
#pragma unroll
        for (int i = 0; i < 4; ++i) {
            int cbase = (i * 4 + wv) * 64;
            __builtin_amdgcn_global_load_lds(
                (const AS1 unsigned int*)(Wc + (size_t)(cbase + lane) * 8),
                (AS3 unsigned int*)(sW + cbase * 8), 16, 0, 0);
        }
#pragma unroll
        for (int i = 0; i < 4; ++i) {
            int cbase = (i * 4 + wv) * 64;
            int id = cbase + lane;
            int r = id >> 4, cs = id & 15;
            int rg = row0 + r; if (rg >= NN) rg = NN - 1;
            int csrc = cs ^ (r & 7);
            __builtin_amdgcn_global_load_lds(
                (const AS1 unsigned int*)(Ac + (size_t)rg * 128 + csrc * 8),
                (AS3 unsigned int*)(sA + cbase * 8), 16, 0, 0);
        }
        asm volatile("s_waitcnt vmcnt(0)" ::: "memory");
        __builtin_amdgcn_sched_barrier(0);
        __syncthreads();

        const int r0 = wv * 16;
#pragma unroll
        for (int ks = 0; ks < 4; ++ks) {
            int cxor = (ks * 4 + g) ^ (m & 7);
            short8 af = *(const short8*)&sA[((r0 + m) * 16 + cxor) * 8];
#pragma unroll
            for (int cb = 0; cb < 4; ++cb) {
                short8 bf = *(const short8*)&sW[((cb * 4 + ks) * 64 + lane) * 8];
                acc[cb] = __builtin_amdgcn_mfma_f32_16x16x32_bf16(af, bf, acc[cb], 0, 0, 0);
            }
        }
    }

    const int rowbase = row0 + wv * 16 + g * 4;
#pragma unroll
    for (int cb = 0; cb < 4; ++cb) {
        int C = col0 + cb * 16 + m;
        float bb = bconv2[C] + bsk2[C];
#pragma unroll
        for (int rr = 0; rr < 4; ++rr) {
            int R = rowbase + rr;
            if (R < NN) out[(size_t)R * 128 + C] = acc[cb][rr] + bb;
        }
    }
}

// ---------------- gather8: 4-edge groups, 16B/lane; result on lanes<16 (8 cols each) ----------------

__device__ __forceinline__ void gather8(const unsigned short* __restrict__ F,
                                        const int* __restrict__ col_idx,
                                        int beg, int end, int grp, size_t lo,
                                        float a[8]) {
#pragma unroll
    for (int i = 0; i < 8; ++i) a[i] = 0.f;
    int j = beg;
#pragma unroll 1
    for (; j + 16 <= end; j += 16) {
        int s[4];
#pragma unroll
        for (int u = 0; u < 4; ++u) s[u] = col_idx[j + 4 * u + grp];
        uint4 v[4];
#pragma unroll
        for (int u = 0; u < 4; ++u)
            v[u] = *(const uint4*)&F[(size_t)s[u] * 128 + lo];
#pragma unroll
        for (int u = 0; u < 4; ++u) {
            a[0] += bf2f((unsigned short)(v[u].x & 0xffff));
            a[1] += bf2f((unsigned short)(v[u].x >> 16));
            a[2] += bf2f((unsigned short)(v[u].y & 0xffff));
            a[3] += bf2f((unsigned short)(v[u].y >> 16));
            a[4] += bf2f((unsigned short)(v[u].z & 0xffff));
            a[5] += bf2f((unsigned short)(v[u].z >> 16));
            a[6] += bf2f((unsigned short)(v[u].w & 0xffff));
            a[7] += bf2f((unsigned short)(v[u].w >> 16));
        }
    }
#pragma unroll 1
    for (; j < end; j += 4) {
        int e = j + grp;
        if (e < end) {
            int s = col_idx[e];
            uint4 v = *(const uint4*)&F[(size_t)s * 128 + lo];
            a[0] += bf2f((unsigned short)(v.x & 0xffff));
            a[1] += bf2f((unsigned short)(v.x >> 16));
            a[2] += bf2f((unsigned short)(v.y & 0xffff));
            a[3] += bf2f((unsigned short)(v.y >> 16));
            a[4] += bf2f((unsigned short)(v.z & 0xffff));
            a[5] += bf2f((unsigned short)(v.z >> 16));
            a[6] += bf2f((unsigned short)(v.w & 0xffff));
            a[7] += bf2f((unsigned short)(v.w >> 16));
        }
    }
#pragma unroll
    for (int i = 0; i < 8; ++i) {
        a[i] += __shfl_xor(a[i], 16);
        a[i] += __shfl_xor(a[i], 32);
    }
}

// ---------------- agg1x: X1 = ELU(C1 + mean(T1) + bc) (wave per node) ----------------

__global__ __launch_bounds__(256)
void k_agg1x(const unsigned short* __restrict__ T1, const int* __restrict__ row_start,
             const int* __restrict__ col_idx, const unsigned short* __restrict__ C1,
             const float* __restrict__ bc, unsigned short* __restrict__ X1out) {
    int node = (blockIdx.x * 256 + threadIdx.x) >> 6;
    int lane = threadIdx.x & 63;
    if (node >= NN) return;
    const int grp = lane >> 4, gl = lane & 15;
    const int beg = row_start[node], end = row_start[node + 1];
    const size_t lo = (size_t)(gl * 8);
    float a[8];
    gather8(T1, col_idx, beg, end, grp, lo, a);
    if (lane < 16) {
        float inv = 1.0f / fmaxf((float)(end - beg), 1.0f);
        uint4 c = *(const uint4*)&C1[(size_t)node * 128 + lo];
        float4 b0 = *(const float4*)&bc[gl * 8];
        float4 b1 = *(const float4*)&bc[gl * 8 + 4];
        float x[8];
        x[0] = a[0] * inv + bf2f((unsigned short)(c.x & 0xffff)) + b0.x;
        x[1] = a[1] * inv + bf2f((unsigned short)(c.x >> 16)) + b0.y;
        x[2] = a[2] * inv + bf2f((unsigned short)(c.y & 0xffff)) + b0.z;
        x[3] = a[3] * inv + bf2f((unsigned short)(c.y >> 16)) + b0.w;
        x[4] = a[4] * inv + bf2f((unsigned short)(c.z & 0xffff)) + b1.x;
        x[5] = a[5] * inv + bf2f((unsigned short)(c.z >> 16)) + b1.y;
        x[6] = a[6] * inv + bf2f((unsigned short)(c.w & 0xffff)) + b1.z;
        x[7] = a[7] * inv + bf2f((unsigned short)(c.w >> 16)) + b1.w;
#pragma unroll
        for (int i = 0; i < 8; ++i)
            x[i] = (x[i] > 0.f) ? x[i] : expm1f(x[i]);
        uint4 o;
        o.x = (unsigned)f2bf(x[0]) | ((unsigned)f2bf(x[1]) << 16);
        o.y = (unsigned)f2bf(x[2]) | ((unsigned)f2bf(x[3]) << 16);
        o.z = (unsigned)f2bf(x[4]) | ((unsigned)f2bf(x[5]) << 16);
        o.w = (unsigned)f2bf(x[6]) | ((unsigned)f2bf(x[7]) << 16);
        *(uint4*)&X1out[(size_t)node * 128 + lo] = o;
    }
}

// ---------------- agg2: AG2 = mean(X3), bf16 out (wave per node) ----------------

__global__ __launch_bounds__(256)
void k_agg2(const unsigned short* __restrict__ X3, const int* __restrict__ row_start,
            const int* __restrict__ col_idx, unsigned short* __restrict__ AG2out) {
    int node = (blockIdx.x * 256 + threadIdx.x) >> 6;
    int lane = threadIdx.x & 63;
    if (node >= NN) return;
    const int grp = lane >> 4, gl = lane & 15;
    const int beg = row_start[node], end = row_start[node + 1];
    const size_t lo = (size_t)(gl * 8);
    float a[8];
    gather8(X3, col_idx, beg, end, grp, lo, a);
    if (lane < 16) {
        float inv = 1.0f / fmaxf((float)(end - beg), 1.0f);
        uint4 o;
        o.x = (unsigned)f2bf(a[0] * inv) | ((unsigned)f2bf(a[1] * inv) << 16);
        o.y = (unsigned)f2bf(a[2] * inv) | ((unsigned)f2bf(a[3] * inv) << 16);
        o.z = (unsigned)f2bf(a[4] * inv) | ((unsigned)f2bf(a[5] * inv) << 16);
        o.w = (unsigned)f2bf(a[6] * inv) | ((unsigned)f2bf(a[7] * inv) << 16);
        *(uint4*)&AG2out[(size_t)node * 128 + lo] = o;
    }
}

// ---------------- launch ----------------

extern "C" void kernel_launch(void* const* d_in, const int* in_sizes, int n_in,
                              void* d_out, int out_size, void* d_ws, size_t ws_size,
                              hipStream_t stream) {
    const float* h        = (const float*)d_in[0];
    const int*   src      = (const int*)d_in[1];
    const int*   dst      = (const int*)d_in[2];
    const float* W_skip1  = (const float*)d_in[3];
    const float* b_skip1  = (const float*)d_in[4];
    const float* W_skip2  = (const float*)d_in[5];
    const float* b_skip2  = (const float*)d_in[6];
    const float* W_self1  = (const float*)d_in[7];
    const float* W_neigh1 = (const float*)d_in[8];
    const float* b_conv1  = (const float*)d_in[9];
    const float* W_si1    = (const float*)d_in[10];
    const float* b_si1    = (const float*)d_in[11];
    const float* W_si2    = (const float*)d_in[12];
    const float* b_si2    = (const float*)d_in[13];
    const float* W_self2  = (const float*)d_in[14];
    const float* W_neigh2 = (const float*)d_in[15];
    const float* b_conv2  = (const float*)d_in[16];
    float* out = (float*)d_out;

    char* ws = (char*)d_ws;
    int* bcnt      = (int*)ws;            // [256]
    int* gcur      = bcnt + 256;          // [256]
    int* bstart    = bcnt + 512;          // [257]
    int* row_start = bcnt + 100096;       // [50001]
    int* col_idx   = bcnt + 150272;       // [800000] -> ends at byte 3801088
    short* wpk          = (short*)(ws + 3801088);            // 8 x 16384 bf16
    unsigned short* hB  = (unsigned short*)(ws + 4063232);   // h -> X1 -> X3
    unsigned short* B1  = (unsigned short*)(ws + 16863232);  // T1 -> Y1 -> AG2
    unsigned short* B2  = (unsigned short*)(ws + 29663232);  // S1
    int* bsrc           = (int*)(ws + 42463232);             // [800000]
    int* bdst           = (int*)(ws + 45663232);             // [800000]
    unsigned short* C1s = (unsigned short*)d_out;            // C1 bf16 scratch (dead before gfinal)

    hipMemsetAsync(ws, 0, 256 * sizeof(int), stream);

    // cvt | bucket-count | packW
    k_prep<<<3125 + NBB + 8, 256, 0, stream>>>(h, hB, dst, bcnt,
                                               W_skip1, W_skip2, W_self1, W_neigh1,
                                               W_si1, W_si2, W_self2, W_neigh2, wpk);
    k_bscan<<<1, NB, 0, stream>>>(bcnt, gcur, bstart);

    // LDS-chunked bucketize
    k_bucket<<<NBB, 256, 0, stream>>>(src, dst, gcur, bsrc, bdst);

    // per-bucket scatter+CSR || triple-GEMM (T1 -> B1, C1 -> C1s, S1 -> B2)
    k_mega1<<<NB + NT, 256, 0, stream>>>(bsrc, bdst, bstart, row_start, col_idx,
                                         hB, wpk, b_skip1, B1, C1s, B2);

    // X1 = ELU(C1 + mean(T1) + bc) -> hB   (wave per node)
    k_agg1x<<<12500, 256, 0, stream>>>(B1, row_start, col_idx, C1s, b_conv1, hB);

    // si1: Y1 = ELU(X1@Wsi1+b) -> B1
    k_mm<1, 0, 0><<<NT, 256, 0, stream>>>(hB, wpk + 4 * 16384, b_si1, B1);
    // si2: X3 = ELU(Y1@Wsi2+b) -> hB
    k_mm<1, 0, 0><<<NT, 256, 0, stream>>>(B1, wpk + 5 * 16384, b_si2, hB);

    // AG2 = mean(X3) -> B1 (bf16, wave per node)
    k_agg2<<<12500, 256, 0, stream>>>(hB, row_start, col_idx, B1);

    // out = X3@Wself2 + AG2@Wneigh2 + S1@Wsk2 + (bconv2+bsk2), write-once f32
    k_gfinal<<<NT, 256, 0, stream>>>(hB, B1, B2, wpk, b_conv2, b_skip2, out);
}